// Round 1
// baseline (2088.773 us; speedup 1.0000x reference)
//
#include <hip/hip_runtime.h>
#include <stdint.h>
#include <math.h>

#define TOK 2048
#define DMODEL 4096
#define DKVW 1024
#define DFF 14336
#define NHEAD 32
#define NKVH 8
#define HDIM 128
#define SEQ 512

typedef float f32x4 __attribute__((ext_vector_type(4)));
typedef short s16x8 __attribute__((ext_vector_type(8)));
typedef unsigned short u16x8 __attribute__((ext_vector_type(8)));

__constant__ float NF4_TAB[16] = {
  -1.0f, -0.6961928009986877f, -0.5250730514526367f, -0.39491748809814453f,
  -0.28444138169288635f, -0.18477343022823334f, -0.09105003625154495f, 0.0f,
  0.07958029955625534f, 0.16093020141124725f, 0.24611230194568634f,
  0.33791524171829224f, 0.44070982933044434f, 0.5626170039176941f,
  0.7229568362236023f, 1.0f };

__device__ __forceinline__ uint16_t f2bf(float f) {
  union { float f; uint32_t u; } x; x.f = f;
  uint32_t r = (x.u + 0x7FFFu + ((x.u >> 16) & 1u)) >> 16;
  return (uint16_t)r;
}
__device__ __forceinline__ float bf2f(uint16_t u) {
  union { uint32_t u; float f; } x; x.u = ((uint32_t)u) << 16;
  return x.f;
}
__device__ __forceinline__ f32x4 mfma16(s16x8 a, s16x8 b, f32x4 c) {
  return __builtin_amdgcn_mfma_f32_16x16x32_bf16(a, b, c, 0, 0, 0);
}
__device__ __forceinline__ void gload_lds16(const void* g, void* l) {
  __builtin_amdgcn_global_load_lds(
    (const __attribute__((address_space(1))) unsigned int*)g,
    (__attribute__((address_space(3))) unsigned int*)l, 16, 0, 0);
}

// ---------------- NF4 dequant -> bf16, pre-swizzled for GEMM LDS tiles ----
__global__ __launch_bounds__(256) void k_dequant(const int* __restrict__ idx,
    const float* __restrict__ am, uint16_t* __restrict__ out, int nelems, int K)
{
  __shared__ float code[16];
  if (threadIdx.x < 16) code[threadIdx.x] = NF4_TAB[threadIdx.x];
  __syncthreads();
  int nch = nelems >> 3;
  int stride = gridDim.x * 256;
  for (int c = blockIdx.x * 256 + threadIdx.x; c < nch; c += stride) {
    int e = c << 3;
    int row = e / K;
    int kc = e - row * K;
    float a = am[c >> 3];
    int4 i0 = *(const int4*)(idx + e);
    int4 i1 = *(const int4*)(idx + e + 4);
    u16x8 pk;
    pk[0] = f2bf(code[i0.x] * a);
    pk[1] = f2bf(code[i0.y] * a);
    pk[2] = f2bf(code[i0.z] * a);
    pk[3] = f2bf(code[i0.w] * a);
    pk[4] = f2bf(code[i1.x] * a);
    pk[5] = f2bf(code[i1.y] * a);
    pk[6] = f2bf(code[i1.z] * a);
    pk[7] = f2bf(code[i1.w] * a);
    int dk = (kc & ~63) | (((((kc >> 3) & 7) ^ (row & 7))) << 3);
    *(u16x8*)(out + (size_t)row * K + dk) = pk;
  }
}

// ------------- fused (embed-gather +) RMSNorm -> bf16 swizzled ------------
__global__ __launch_bounds__(256) void k_rms(const int* __restrict__ ids,
    const float* __restrict__ table, const float* __restrict__ hin,
    const float* __restrict__ w, float* __restrict__ hout,
    uint16_t* __restrict__ r, int useEmbed)
{
  int t = blockIdx.x, tid = threadIdx.x;
  int wv = tid >> 6, l = tid & 63;
  const float* src = useEmbed ? (table + (size_t)ids[t] * DMODEL)
                              : (hin + (size_t)t * DMODEL);
  int d0 = tid * 16;
  float vals[16];
  float ss = 0.f;
  #pragma unroll
  for (int i = 0; i < 4; ++i) {
    float4 v4 = *(const float4*)(src + d0 + i * 4);
    vals[i*4+0] = v4.x; vals[i*4+1] = v4.y; vals[i*4+2] = v4.z; vals[i*4+3] = v4.w;
    ss += v4.x*v4.x + v4.y*v4.y + v4.z*v4.z + v4.w*v4.w;
  }
  #pragma unroll
  for (int off = 1; off < 64; off <<= 1) ss += __shfl_xor(ss, off);
  __shared__ float red[4];
  if (l == 0) red[wv] = ss;
  __syncthreads();
  float rs = rsqrtf((red[0]+red[1]+red[2]+red[3]) * (1.f/DMODEL) + 1e-5f);
  if (useEmbed) {
    #pragma unroll
    for (int i = 0; i < 4; ++i) {
      float4 v4;
      v4.x = vals[i*4+0]; v4.y = vals[i*4+1]; v4.z = vals[i*4+2]; v4.w = vals[i*4+3];
      *(float4*)(hout + (size_t)t * DMODEL + d0 + i * 4) = v4;
    }
  }
  #pragma unroll
  for (int cth = 0; cth < 2; ++cth) {
    int dd = d0 + cth * 8;
    u16x8 pk;
    #pragma unroll
    for (int j = 0; j < 8; ++j) pk[j] = f2bf(vals[cth*8+j] * rs * w[dd + j]);
    int dsw = (dd & ~63) | (((((dd >> 3) & 7) ^ (t & 7))) << 3);
    *(u16x8*)(r + (size_t)t * DMODEL + dsw) = pk;
  }
}

// ------------------------------- RoPE in-place ----------------------------
__global__ __launch_bounds__(256) void k_rope(uint16_t* __restrict__ x, int nh, int lognh)
{
  int gid = blockIdx.x * 256 + threadIdx.x;
  int total = TOK * nh * 64;
  if (gid >= total) return;
  int j = gid & 63;
  int rest = gid >> 6;
  int hh = rest & (nh - 1);
  int t = rest >> lognh;
  int s = t & (SEQ - 1);
  float inv = expf(-(float)j * 0.14391156831212787f); // ln(10000)/64
  float f = (float)s * inv;
  float sn, cs;
  sincosf(f, &sn, &cs);
  uint16_t* p = x + (size_t)t * nh * HDIM + hh * HDIM + j;
  float x1 = bf2f(p[0]), x2 = bf2f(p[64]);
  p[0]  = f2bf(x1 * cs - x2 * sn);
  p[64] = f2bf(x2 * cs + x1 * sn);
}

// ------------- GEMM: Y = A(MxK, swz bf16) * W(NxK, swz bf16)^T ------------
// EPI: 0 = bf16 linear store; 1 = silu -> bf16 linear; 2 = (aux * c) -> bf16
// swizzled store; 3 = f32 += (residual add)
template<int EPI>
__global__ __launch_bounds__(256) void k_gemm(
    const uint16_t* __restrict__ A, const uint16_t* __restrict__ W,
    int N, int K, uint16_t* __restrict__ outb, float* __restrict__ outf,
    const uint16_t* __restrict__ aux)
{
  __shared__ uint16_t As[128 * 64];
  __shared__ uint16_t Bs[128 * 64];
  const int n0 = blockIdx.x * 128, m0 = blockIdx.y * 128;
  const int tid = threadIdx.x;
  const int wv = tid >> 6, l = tid & 63;
  const int wr = wv >> 1, wc = wv & 1;
  const f32x4 Z4 = {0.f, 0.f, 0.f, 0.f};
  f32x4 acc[4][4];
  #pragma unroll
  for (int i = 0; i < 4; ++i)
    #pragma unroll
    for (int j = 0; j < 4; ++j) acc[i][j] = Z4;

  for (int k0 = 0; k0 < K; k0 += 64) {
    __syncthreads();
    #pragma unroll
    for (int i = 0; i < 4; ++i) {
      int boff = (wv * 4 + i) * 1024;
      int pl = boff + l * 16;
      int row = pl >> 7, cb = pl & 127;
      gload_lds16((const char*)A + ((size_t)(m0 + row) * K + k0) * 2 + cb,
                  (char*)As + boff);
      gload_lds16((const char*)W + ((size_t)(n0 + row) * K + k0) * 2 + cb,
                  (char*)Bs + boff);
    }
    __syncthreads();
    #pragma unroll
    for (int kk = 0; kk < 2; ++kk) {
      s16x8 af[4], bf[4];
      #pragma unroll
      for (int mi = 0; mi < 4; ++mi) {
        int row = wr * 64 + mi * 16 + (l & 15);
        int cb = (kk * 64 + ((l >> 4) << 4)) ^ ((row & 7) << 4);
        af[mi] = *(const s16x8*)((const char*)As + row * 128 + cb);
      }
      #pragma unroll
      for (int ni = 0; ni < 4; ++ni) {
        int row = wc * 64 + ni * 16 + (l & 15);
        int cb = (kk * 64 + ((l >> 4) << 4)) ^ ((row & 7) << 4);
        bf[ni] = *(const s16x8*)((const char*)Bs + row * 128 + cb);
      }
      #pragma unroll
      for (int mi = 0; mi < 4; ++mi)
        #pragma unroll
        for (int ni = 0; ni < 4; ++ni)
          acc[mi][ni] = mfma16(af[mi], bf[ni], acc[mi][ni]);
    }
  }
  #pragma unroll
  for (int mi = 0; mi < 4; ++mi)
    #pragma unroll
    for (int ni = 0; ni < 4; ++ni)
      #pragma unroll
      for (int r = 0; r < 4; ++r) {
        int row = m0 + wr * 64 + mi * 16 + ((l >> 4) << 2) + r;
        int col = n0 + wc * 64 + ni * 16 + (l & 15);
        float c = acc[mi][ni][r];
        if (EPI == 0) {
          outb[(size_t)row * N + col] = f2bf(c);
        } else if (EPI == 1) {
          outb[(size_t)row * N + col] = f2bf(c / (1.f + __expf(-c)));
        } else if (EPI == 2) {
          float g = bf2f(aux[(size_t)row * N + col]);
          outb[(size_t)row * N + (col ^ ((row & 7) << 3))] = f2bf(g * c);
        } else {
          outf[(size_t)row * N + col] += c;
        }
      }
}

// ------------------------- flash attention (GQA) --------------------------
__global__ __launch_bounds__(256) void k_attn(
    const uint16_t* __restrict__ qp, const uint16_t* __restrict__ kp,
    const uint16_t* __restrict__ vp, const int* __restrict__ maskp,
    uint16_t* __restrict__ aop)
{
  int qb = blockIdx.x, hh = blockIdx.y, b = blockIdx.z;
  int tid = threadIdx.x;
  int wv = tid >> 6, l = tid & 63;
  int kvh = hh >> 2;
  __shared__ uint16_t Qs[64 * 128];
  __shared__ uint16_t Ks[64 * 128];
  __shared__ uint16_t Vt[128 * 64];
  __shared__ uint16_t Ps[64 * 64];
  __shared__ float mkf[64];
  const int t0 = b * SEQ + qb * 64;
  // stage Q (swizzled rows of 256B)
  #pragma unroll
  for (int c = 0; c < 4; ++c) {
    int fc = c * 256 + tid;
    int row = fc >> 4, dcol = (fc & 15) << 3;
    u16x8 val = *(const u16x8*)(qp + (size_t)(t0 + row) * DMODEL + hh * HDIM + dcol);
    *(u16x8*)((char*)Qs + row * 256 + ((dcol << 1) ^ ((row & 7) << 4))) = val;
  }
  const f32x4 Z4 = {0.f, 0.f, 0.f, 0.f};
  f32x4 o[8];
  float mrun[4], lrun[4];
  #pragma unroll
  for (int i = 0; i < 8; ++i) o[i] = Z4;
  #pragma unroll
  for (int i = 0; i < 4; ++i) { mrun[i] = -1e30f; lrun[i] = 0.f; }
  const float sc = 0.08838834764831845f; // 1/sqrt(128)

  for (int kc = 0; kc <= qb; ++kc) {
    __syncthreads();
    #pragma unroll
    for (int c = 0; c < 4; ++c) {
      int fc = c * 256 + tid;
      int row = fc >> 4, dcol = (fc & 15) << 3;
      u16x8 val = *(const u16x8*)(kp + (size_t)(b * SEQ + kc * 64 + row) * DKVW + kvh * HDIM + dcol);
      *(u16x8*)((char*)Ks + row * 256 + ((dcol << 1) ^ ((row & 7) << 4))) = val;
    }
    #pragma unroll
    for (int c = 0; c < 4; ++c) {
      int fc = c * 256 + tid;
      int kr = fc >> 4, dc0 = (fc & 15) << 3;
      u16x8 val = *(const u16x8*)(vp + (size_t)(b * SEQ + kc * 64 + kr) * DKVW + kvh * HDIM + dc0);
      #pragma unroll
      for (int jj = 0; jj < 8; ++jj) {
        int dd = dc0 + jj;
        *(uint16_t*)((char*)Vt + dd * 128 + ((kr << 1) ^ ((dd & 7) << 4))) = val[jj];
      }
    }
    if (tid < 64) mkf[tid] = (maskp[b * SEQ + kc * 64 + tid] > 0) ? 1.f : 0.f;
    __syncthreads();
    // S = Q K^T
    f32x4 sf[4];
    #pragma unroll
    for (int i = 0; i < 4; ++i) sf[i] = Z4;
    #pragma unroll
    for (int ds = 0; ds < 4; ++ds) {
      int arow = wv * 16 + (l & 15);
      int acb = (ds * 64 + ((l >> 4) << 4)) ^ ((arow & 7) << 4);
      s16x8 af = *(const s16x8*)((const char*)Qs + arow * 256 + acb);
      #pragma unroll
      for (int ni = 0; ni < 4; ++ni) {
        int brow = ni * 16 + (l & 15);
        int bcb = (ds * 64 + ((l >> 4) << 4)) ^ ((brow & 7) << 4);
        s16x8 bf = *(const s16x8*)((const char*)Ks + brow * 256 + bcb);
        sf[ni] = mfma16(af, bf, sf[ni]);
      }
    }
    // online softmax
    #pragma unroll
    for (int r = 0; r < 4; ++r) {
      int rloc = wv * 16 + ((l >> 4) << 2) + r;
      int qabs = qb * 64 + rloc;
      float vals[4];
      float vmax = -1e30f;
      #pragma unroll
      for (int ni = 0; ni < 4; ++ni) {
        int kl = ni * 16 + (l & 15);
        int kabs = kc * 64 + kl;
        bool ok = (kabs <= qabs) && (mkf[kl] > 0.5f);
        vals[ni] = ok ? sf[ni][r] * sc : -1e9f;
        vmax = fmaxf(vmax, vals[ni]);
      }
      #pragma unroll
      for (int off = 1; off < 16; off <<= 1) vmax = fmaxf(vmax, __shfl_xor(vmax, off));
      float mnew = fmaxf(mrun[r], vmax);
      float alpha = __expf(mrun[r] - mnew);
      mrun[r] = mnew;
      float ps = 0.f;
      #pragma unroll
      for (int ni = 0; ni < 4; ++ni) {
        float pe = __expf(vals[ni] - mnew);
        ps += pe;
        int colb = (ni * 16 + (l & 15)) << 1;
        *(uint16_t*)((char*)Ps + rloc * 128 + (colb ^ ((rloc & 7) << 4))) = f2bf(pe);
      }
      #pragma unroll
      for (int off = 1; off < 16; off <<= 1) ps += __shfl_xor(ps, off);
      lrun[r] = lrun[r] * alpha + ps;
      #pragma unroll
      for (int dn = 0; dn < 8; ++dn) o[dn][r] *= alpha;
    }
    __syncthreads();
    // O += P V
    #pragma unroll
    for (int kk = 0; kk < 2; ++kk) {
      int prow = wv * 16 + (l & 15);
      int pcb = (kk * 64 + ((l >> 4) << 4)) ^ ((prow & 7) << 4);
      s16x8 pf = *(const s16x8*)((const char*)Ps + prow * 128 + pcb);
      #pragma unroll
      for (int dn = 0; dn < 8; ++dn) {
        int vrow = dn * 16 + (l & 15);
        int vcb = (kk * 64 + ((l >> 4) << 4)) ^ ((vrow & 7) << 4);
        s16x8 vf = *(const s16x8*)((const char*)Vt + vrow * 128 + vcb);
        o[dn] = mfma16(pf, vf, o[dn]);
      }
    }
  }
  // epilogue: ao written pre-swizzled for the O-proj GEMM
  #pragma unroll
  for (int r = 0; r < 4; ++r) {
    float inv = 1.f / lrun[r];
    int t = t0 + wv * 16 + ((l >> 4) << 2) + r;
    #pragma unroll
    for (int dn = 0; dn < 8; ++dn) {
      int dloc = dn * 16 + (l & 15);
      aop[(size_t)t * DMODEL + hh * HDIM + (dloc ^ ((t & 7) << 3))] = f2bf(o[dn][r] * inv);
    }
  }
}

// ------------------ last-token pool + normalize + project -----------------
__global__ __launch_bounds__(256) void k_pool(const float* __restrict__ h,
    const int* __restrict__ maskp, const float* __restrict__ dpw,
    const float* __restrict__ dpb, float* __restrict__ out)
{
  int i = blockIdx.x; // 0,1
  int tid = threadIdx.x, wv = tid >> 6, l = tid & 63;
  __shared__ float p1[4096];
  __shared__ float p2[4096];
  __shared__ float red[8];
  __shared__ int lastsh[2];
  if (tid < 2) {
    int b = i + tid * 2;
    int s = 0;
    for (int j = 0; j < 512; ++j) s += (maskp[b * 512 + j] > 0);
    lastsh[tid] = s - 1;
  }
  __syncthreads();
  const float* r1 = h + ((size_t)(i * 512 + lastsh[0])) * 4096;
  const float* r2 = h + ((size_t)((i + 2) * 512 + lastsh[1])) * 4096;
  float ss1 = 0.f, ss2 = 0.f;
  for (int d = tid; d < 4096; d += 256) {
    float a = r1[d], bb = r2[d];
    p1[d] = a; p2[d] = bb;
    ss1 += a * a; ss2 += bb * bb;
  }
  #pragma unroll
  for (int off = 1; off < 64; off <<= 1) {
    ss1 += __shfl_xor(ss1, off);
    ss2 += __shfl_xor(ss2, off);
  }
  if (l == 0) { red[wv] = ss1; red[4 + wv] = ss2; }
  __syncthreads();
  float n1 = fmaxf(sqrtf(red[0] + red[1] + red[2] + red[3]), 1e-12f);
  float n2 = fmaxf(sqrtf(red[4] + red[5] + red[6] + red[7]), 1e-12f);
  for (int oidx = wv; oidx < 50; oidx += 4) {
    float d1 = 0.f, d2 = 0.f;
    for (int d = l; d < 4096; d += 64) {
      float wval = dpw[(size_t)oidx * 4096 + d];
      d1 += wval * p1[d];
      d2 += wval * p2[d];
    }
    #pragma unroll
    for (int off = 1; off < 64; off <<= 1) {
      d1 += __shfl_xor(d1, off);
      d2 += __shfl_xor(d2, off);
    }
    if (l == 0) out[i * 50 + oidx] = (d1 / n1 + dpb[oidx]) * (d2 / n2 + dpb[oidx]);
  }
}

// ---------------------------------------------------------------------------
extern "C" void kernel_launch(void* const* d_in, const int* in_sizes, int n_in,
                              void* d_out, int out_size, void* d_ws, size_t ws_size,
                              hipStream_t stream) {
  const int*   ids   = (const int*)d_in[0];
  const int*   maskp = (const int*)d_in[1];
  const float* table = (const float*)d_in[2];
  const int* idxp[7];
  const float* amp[7];
  // setup_inputs() interleaves idx_X / absmax_X; detect via sizes for safety.
  if (in_sizes[4] == in_sizes[3] / 64) {
    for (int i = 0; i < 7; ++i) {
      idxp[i] = (const int*)d_in[3 + 2 * i];
      amp[i]  = (const float*)d_in[4 + 2 * i];
    }
  } else {
    for (int i = 0; i < 7; ++i) {
      idxp[i] = (const int*)d_in[3 + i];
      amp[i]  = (const float*)d_in[10 + i];
    }
  }
  const float* rms1 = (const float*)d_in[17];
  const float* rms2 = (const float*)d_in[18];
  const float* dpw  = (const float*)d_in[19];
  const float* dpb  = (const float*)d_in[20];
  float* out = (float*)d_out;

  char* p = (char*)d_ws;
  uint16_t* wbuf  = (uint16_t*)p; p += (size_t)DFF * DMODEL * 2;   // 112 MiB
  float*    hbuf  = (float*)p;    p += (size_t)TOK * DMODEL * 4;   // 32 MiB
  uint16_t* rbuf  = (uint16_t*)p; p += (size_t)TOK * DMODEL * 2;
  uint16_t* qbuf  = (uint16_t*)p; p += (size_t)TOK * DMODEL * 2;
  uint16_t* kbuf  = (uint16_t*)p; p += (size_t)TOK * DKVW * 2;
  uint16_t* vbuf  = (uint16_t*)p; p += (size_t)TOK * DKVW * 2;
  uint16_t* aobuf = (uint16_t*)p; p += (size_t)TOK * DMODEL * 2;
  uint16_t* r2buf = (uint16_t*)p; p += (size_t)TOK * DMODEL * 2;
  uint16_t* gbuf  = (uint16_t*)p; p += (size_t)TOK * DFF * 2;      // 56 MiB
  uint16_t* hmbuf = (uint16_t*)p; p += (size_t)TOK * DFF * 2;      // 56 MiB
  // total ~344 MB of ws

  // embed + rmsnorm1
  k_rms<<<TOK, 256, 0, stream>>>(ids, table, nullptr, rms1, hbuf, rbuf, 1);

  // Q/K/V projections
  k_dequant<<<4096, 256, 0, stream>>>(idxp[0], amp[0], wbuf, DMODEL * DMODEL, DMODEL);
  k_gemm<0><<<dim3(DMODEL / 128, TOK / 128), 256, 0, stream>>>(rbuf, wbuf, DMODEL, DMODEL, qbuf, nullptr, nullptr);
  k_dequant<<<4096, 256, 0, stream>>>(idxp[1], amp[1], wbuf, DKVW * DMODEL, DMODEL);
  k_gemm<0><<<dim3(DKVW / 128, TOK / 128), 256, 0, stream>>>(rbuf, wbuf, DKVW, DMODEL, kbuf, nullptr, nullptr);
  k_dequant<<<4096, 256, 0, stream>>>(idxp[2], amp[2], wbuf, DKVW * DMODEL, DMODEL);
  k_gemm<0><<<dim3(DKVW / 128, TOK / 128), 256, 0, stream>>>(rbuf, wbuf, DKVW, DMODEL, vbuf, nullptr, nullptr);

  // RoPE
  k_rope<<<(TOK * NHEAD * 64) / 256, 256, 0, stream>>>(qbuf, NHEAD, 5);
  k_rope<<<(TOK * NKVH * 64) / 256, 256, 0, stream>>>(kbuf, NKVH, 3);

  // attention
  k_attn<<<dim3(SEQ / 64, NHEAD, 4), 256, 0, stream>>>(qbuf, kbuf, vbuf, maskp, aobuf);

  // O projection, residual add into h
  k_dequant<<<4096, 256, 0, stream>>>(idxp[3], amp[3], wbuf, DMODEL * DMODEL, DMODEL);
  k_gemm<3><<<dim3(DMODEL / 128, TOK / 128), 256, 0, stream>>>(aobuf, wbuf, DMODEL, DMODEL, nullptr, hbuf, nullptr);

  // rmsnorm2
  k_rms<<<TOK, 256, 0, stream>>>(nullptr, nullptr, hbuf, rms2, nullptr, r2buf, 0);

  // MLP
  k_dequant<<<4096, 256, 0, stream>>>(idxp[4], amp[4], wbuf, DFF * DMODEL, DMODEL);
  k_gemm<1><<<dim3(DFF / 128, TOK / 128), 256, 0, stream>>>(r2buf, wbuf, DFF, DMODEL, gbuf, nullptr, nullptr);
  k_dequant<<<4096, 256, 0, stream>>>(idxp[5], amp[5], wbuf, DFF * DMODEL, DMODEL);
  k_gemm<2><<<dim3(DFF / 128, TOK / 128), 256, 0, stream>>>(r2buf, wbuf, DFF, DMODEL, hmbuf, nullptr, gbuf);
  k_dequant<<<4096, 256, 0, stream>>>(idxp[6], amp[6], wbuf, DMODEL * DFF, DFF);
  k_gemm<3><<<dim3(DMODEL / 128, TOK / 128), 256, 0, stream>>>(hmbuf, wbuf, DMODEL, DFF, nullptr, hbuf, nullptr);

  // pool + normalize + project + pairwise product
  k_pool<<<2, 256, 0, stream>>>(hbuf, maskp, dpw, dpb, out);
}

// Round 2
// 2022.792 us; speedup vs baseline: 1.0326x; 1.0326x over previous
//
#include <hip/hip_runtime.h>
#include <stdint.h>
#include <math.h>

#define TOK 2048
#define DMODEL 4096
#define DKVW 1024
#define DFF 14336
#define NHEAD 32
#define NKVH 8
#define HDIM 128
#define SEQ 512

typedef float f32x4 __attribute__((ext_vector_type(4)));
typedef short s16x8 __attribute__((ext_vector_type(8)));
typedef unsigned short u16x8 __attribute__((ext_vector_type(8)));

__constant__ float NF4_TAB[16] = {
  -1.0f, -0.6961928009986877f, -0.5250730514526367f, -0.39491748809814453f,
  -0.28444138169288635f, -0.18477343022823334f, -0.09105003625154495f, 0.0f,
  0.07958029955625534f, 0.16093020141124725f, 0.24611230194568634f,
  0.33791524171829224f, 0.44070982933044434f, 0.5626170039176941f,
  0.7229568362236023f, 1.0f };

__device__ __forceinline__ uint16_t f2bf(float f) {
  union { float f; uint32_t u; } x; x.f = f;
  uint32_t r = (x.u + 0x7FFFu + ((x.u >> 16) & 1u)) >> 16;
  return (uint16_t)r;
}
__device__ __forceinline__ float bf2f(uint16_t u) {
  union { uint32_t u; float f; } x; x.u = ((uint32_t)u) << 16;
  return x.f;
}
__device__ __forceinline__ f32x4 mfma16(s16x8 a, s16x8 b, f32x4 c) {
  return __builtin_amdgcn_mfma_f32_16x16x32_bf16(a, b, c, 0, 0, 0);
}
__device__ __forceinline__ void gload_lds16(const void* g, void* l) {
  __builtin_amdgcn_global_load_lds(
    (const __attribute__((address_space(1))) unsigned int*)g,
    (__attribute__((address_space(3))) unsigned int*)l, 16, 0, 0);
}

// ---------------- NF4 dequant -> bf16, pre-swizzled for GEMM LDS tiles ----
__global__ __launch_bounds__(256) void k_dequant(const int* __restrict__ idx,
    const float* __restrict__ am, uint16_t* __restrict__ out, int nelems, int K)
{
  __shared__ float code[16];
  if (threadIdx.x < 16) code[threadIdx.x] = NF4_TAB[threadIdx.x];
  __syncthreads();
  int nch = nelems >> 3;
  int stride = gridDim.x * 256;
  for (int c = blockIdx.x * 256 + threadIdx.x; c < nch; c += stride) {
    int e = c << 3;
    int row = e / K;
    int kc = e - row * K;
    float a = am[c >> 3];
    int4 i0 = *(const int4*)(idx + e);
    int4 i1 = *(const int4*)(idx + e + 4);
    u16x8 pk;
    pk[0] = f2bf(code[i0.x] * a);
    pk[1] = f2bf(code[i0.y] * a);
    pk[2] = f2bf(code[i0.z] * a);
    pk[3] = f2bf(code[i0.w] * a);
    pk[4] = f2bf(code[i1.x] * a);
    pk[5] = f2bf(code[i1.y] * a);
    pk[6] = f2bf(code[i1.z] * a);
    pk[7] = f2bf(code[i1.w] * a);
    int dk = (kc & ~63) | (((((kc >> 3) & 7) ^ (row & 7))) << 3);
    *(u16x8*)(out + (size_t)row * K + dk) = pk;
  }
}

// ------------- fused (embed-gather +) RMSNorm -> bf16 swizzled ------------
__global__ __launch_bounds__(256) void k_rms(const int* __restrict__ ids,
    const float* __restrict__ table, const float* __restrict__ hin,
    const float* __restrict__ w, float* __restrict__ hout,
    uint16_t* __restrict__ r, int useEmbed)
{
  int t = blockIdx.x, tid = threadIdx.x;
  int wv = tid >> 6, l = tid & 63;
  const float* src = useEmbed ? (table + (size_t)ids[t] * DMODEL)
                              : (hin + (size_t)t * DMODEL);
  int d0 = tid * 16;
  float vals[16];
  float ss = 0.f;
  #pragma unroll
  for (int i = 0; i < 4; ++i) {
    float4 v4 = *(const float4*)(src + d0 + i * 4);
    vals[i*4+0] = v4.x; vals[i*4+1] = v4.y; vals[i*4+2] = v4.z; vals[i*4+3] = v4.w;
    ss += v4.x*v4.x + v4.y*v4.y + v4.z*v4.z + v4.w*v4.w;
  }
  #pragma unroll
  for (int off = 1; off < 64; off <<= 1) ss += __shfl_xor(ss, off);
  __shared__ float red[4];
  if (l == 0) red[wv] = ss;
  __syncthreads();
  float rs = rsqrtf((red[0]+red[1]+red[2]+red[3]) * (1.f/DMODEL) + 1e-5f);
  if (useEmbed) {
    #pragma unroll
    for (int i = 0; i < 4; ++i) {
      float4 v4;
      v4.x = vals[i*4+0]; v4.y = vals[i*4+1]; v4.z = vals[i*4+2]; v4.w = vals[i*4+3];
      *(float4*)(hout + (size_t)t * DMODEL + d0 + i * 4) = v4;
    }
  }
  #pragma unroll
  for (int cth = 0; cth < 2; ++cth) {
    int dd = d0 + cth * 8;
    u16x8 pk;
    #pragma unroll
    for (int j = 0; j < 8; ++j) pk[j] = f2bf(vals[cth*8+j] * rs * w[dd + j]);
    int dsw = (dd & ~63) | (((((dd >> 3) & 7) ^ (t & 7))) << 3);
    *(u16x8*)(r + (size_t)t * DMODEL + dsw) = pk;
  }
}

// ------------------------------- RoPE in-place ----------------------------
__global__ __launch_bounds__(256) void k_rope2(uint16_t* __restrict__ x,
    int nh, int lognh, int rs)
{
  int gid = blockIdx.x * 256 + threadIdx.x;
  int j = gid & 63;
  int rest = gid >> 6;
  int hh = rest & (nh - 1);
  int t = rest >> lognh;
  if (t >= TOK) return;
  int s = t & (SEQ - 1);
  float inv = expf(-(float)j * 0.14391156831212787f); // ln(10000)/64
  float f = (float)s * inv;
  float sn, cs;
  sincosf(f, &sn, &cs);
  uint16_t* p = x + (size_t)t * rs + hh * HDIM + j;
  float x1 = bf2f(p[0]), x2 = bf2f(p[64]);
  p[0]  = f2bf(x1 * cs - x2 * sn);
  p[64] = f2bf(x2 * cs + x1 * sn);
}

// ======================= 8-phase 256xBN GEMM (T2+T3+T4+T5) ================
// Y = A(MxK, swz bf16) * W(NxK, swz bf16)^T.  BM=256, BK=64, 8 waves (2x4).
// Per-wave: 128 rows (interleaved 16-row groups 2*mf+wr) x BN/4 cols.
// LDS: A 2x32KB dbuf; B 2x(BN*128B) dbuf. Stage via global_load_lds (linear,
// sources pre-swizzled); counted vmcnt (6 for BN=256, 4 for BN=128).
// EPI: 0 bf16 store; 1 silu->bf16; 2 (aux*c)->bf16 swizzled; 3 f32 +=
template<int BN, int EPI>
__global__ __launch_bounds__(512, 2) void k_gemm2(
    const uint16_t* __restrict__ A, const uint16_t* __restrict__ W,
    int N, int K, uint16_t* __restrict__ outb, float* __restrict__ outf,
    const uint16_t* __restrict__ aux)
{
  constexpr int NREP = BN / 64;
  __shared__ __align__(1024) uint16_t As_[2 * 256 * 64];
  __shared__ __align__(1024) uint16_t Bs_[2 * BN * 64];
  const int tid = threadIdx.x;
  const int wid = tid >> 6, l = tid & 63;
  const int wr = wid >> 2, wc = wid & 3;
  const int n0 = blockIdx.x * BN, m0 = blockIdx.y * 256;
  const int NT = K >> 6;
  const int lrow = l >> 3, lcb = (l & 7) * 16;

  auto stA = [&](int t, int h) {
    int ta = (t < NT) ? t : (t - NT);
    const char* g = (const char*)A +
        ((size_t)(m0 + h * 128 + wid * 16 + lrow) * K + ta * 64) * 2 + lcb;
    char* s = (char*)As_ + (t & 1) * 32768 + h * 16384 + wid * 2048;
    gload_lds16(g, s);
    gload_lds16(g + (size_t)8 * K * 2, s + 1024);
  };
  auto stB = [&](int t, int h) {
    int ta = (t < NT) ? t : (t - NT);
    if constexpr (BN == 256) {
      const char* g = (const char*)W +
          ((size_t)(n0 + h * 128 + wid * 16 + lrow) * K + ta * 64) * 2 + lcb;
      char* s = (char*)Bs_ + (t & 1) * 32768 + h * 16384 + wid * 2048;
      gload_lds16(g, s);
      gload_lds16(g + (size_t)8 * K * 2, s + 1024);
    } else {
      const char* g = (const char*)W +
          ((size_t)(n0 + h * 64 + wid * 8 + lrow) * K + ta * 64) * 2 + lcb;
      char* s = (char*)Bs_ + (t & 1) * 16384 + h * 8192 + wid * 1024;
      gload_lds16(g, s);
    }
  };

  const int cb0 = (((l >> 4) << 4)) ^ ((l & 7) << 4);
  const int cb1 = (64 + ((l >> 4) << 4)) ^ ((l & 7) << 4);

  const f32x4 Z4 = {0.f, 0.f, 0.f, 0.f};
  f32x4 acc[8][NREP];
  #pragma unroll
  for (int i = 0; i < 8; ++i)
    #pragma unroll
    for (int j = 0; j < NREP; ++j) acc[i][j] = Z4;
  s16x8 bfr[NREP][2];

#define VMW do { if constexpr (BN == 256) \
      asm volatile("s_waitcnt vmcnt(6)" ::: "memory"); \
    else asm volatile("s_waitcnt vmcnt(4)" ::: "memory"); } while (0)

#define PHASE(DB, Q, READB, STG) {                                          \
    const char* abase = (const char*)As_ + (DB) * 32768;                    \
    s16x8 af[2][2];                                                         \
    _Pragma("unroll") for (int mm = 0; mm < 2; ++mm) {                      \
      int arow = ((2 * (2 * (Q) + mm) + wr) * 16 + (l & 15)) * 128;         \
      af[mm][0] = *(const s16x8*)(abase + arow + cb0);                      \
      af[mm][1] = *(const s16x8*)(abase + arow + cb1);                      \
    }                                                                       \
    if (READB) {                                                            \
      const char* bbase = (const char*)Bs_ + (DB) * (BN * 128);             \
      _Pragma("unroll") for (int nn = 0; nn < NREP; ++nn) {                 \
        int brow = (wc * (BN / 4) + nn * 16 + (l & 15)) * 128;              \
        bfr[nn][0] = *(const s16x8*)(bbase + brow + cb0);                   \
        bfr[nn][1] = *(const s16x8*)(bbase + brow + cb1);                   \
      }                                                                     \
    }                                                                       \
    STG;                                                                    \
    __builtin_amdgcn_s_barrier();                                           \
    asm volatile("s_waitcnt lgkmcnt(0)" ::: "memory");                      \
    __builtin_amdgcn_sched_barrier(0);                                      \
    __builtin_amdgcn_s_setprio(1);                                          \
    _Pragma("unroll") for (int mm = 0; mm < 2; ++mm)                        \
      _Pragma("unroll") for (int nn = 0; nn < NREP; ++nn) {                 \
        acc[2 * (Q) + mm][nn] = mfma16(af[mm][0], bfr[nn][0], acc[2 * (Q) + mm][nn]); \
        acc[2 * (Q) + mm][nn] = mfma16(af[mm][1], bfr[nn][1], acc[2 * (Q) + mm][nn]); \
      }                                                                     \
    __builtin_amdgcn_s_setprio(0);                                          \
    __builtin_amdgcn_s_barrier();                                           \
  }

  // prologue: T0 fully + T1 minus A-half1; wait T0 landed
  stB(0, 0); stA(0, 0); stB(0, 1); stA(0, 1);
  stB(1, 0); stA(1, 0); stB(1, 1);
  VMW;
  __builtin_amdgcn_s_barrier();

  const int NI = NT >> 1;
  for (int it = 0; it < NI; ++it) {
    int t0 = 2 * it, t1 = t0 + 1;
    PHASE(0, 0, 1, stA(t1, 1));                 // ph1: reads buf0 A-h0 + all B
    PHASE(0, 1, 0, stB(t0 + 2, 0));             // ph2: A-h0
    PHASE(0, 2, 0, stA(t0 + 2, 0));             // ph3: A-h1
    PHASE(0, 3, 0, { stB(t0 + 2, 1); VMW; });   // ph4: A-h1, vmcnt
    PHASE(1, 0, 1, stA(t0 + 2, 1));             // ph5
    PHASE(1, 1, 0, stB(t1 + 2, 0));             // ph6
    PHASE(1, 2, 0, stA(t1 + 2, 0));             // ph7
    PHASE(1, 3, 0, { stB(t1 + 2, 1); VMW; });   // ph8
  }
  asm volatile("s_waitcnt vmcnt(0)" ::: "memory");
  __builtin_amdgcn_s_barrier();
#undef PHASE
#undef VMW

  #pragma unroll
  for (int mf = 0; mf < 8; ++mf)
    #pragma unroll
    for (int nf = 0; nf < NREP; ++nf)
      #pragma unroll
      for (int r = 0; r < 4; ++r) {
        int row = m0 + (2 * mf + wr) * 16 + ((l >> 4) << 2) + r;
        int col = n0 + wc * (BN / 4) + nf * 16 + (l & 15);
        float c = acc[mf][nf][r];
        if (EPI == 0) {
          outb[(size_t)row * N + col] = f2bf(c);
        } else if (EPI == 1) {
          outb[(size_t)row * N + col] = f2bf(c / (1.f + __expf(-c)));
        } else if (EPI == 2) {
          float g = bf2f(aux[(size_t)row * N + col]);
          outb[(size_t)row * N + (col ^ ((row & 7) << 3))] = f2bf(g * c);
        } else {
          outf[(size_t)row * N + col] += c;
        }
      }
}

// ------------------------- flash attention (GQA) --------------------------
__global__ __launch_bounds__(256) void k_attn(
    const uint16_t* __restrict__ qp, const uint16_t* __restrict__ kp,
    const uint16_t* __restrict__ vp, const int* __restrict__ maskp,
    uint16_t* __restrict__ aop, int qs, int ks)
{
  int qb = blockIdx.x, hh = blockIdx.y, b = blockIdx.z;
  int tid = threadIdx.x;
  int wv = tid >> 6, l = tid & 63;
  int kvh = hh >> 2;
  __shared__ uint16_t Qs[64 * 128];
  __shared__ uint16_t Ks[64 * 128];
  __shared__ uint16_t Vt[128 * 64];
  __shared__ uint16_t Ps[64 * 64];
  __shared__ float mkf[64];
  const int t0 = b * SEQ + qb * 64;
  #pragma unroll
  for (int c = 0; c < 4; ++c) {
    int fc = c * 256 + tid;
    int row = fc >> 4, dcol = (fc & 15) << 3;
    u16x8 val = *(const u16x8*)(qp + (size_t)(t0 + row) * qs + hh * HDIM + dcol);
    *(u16x8*)((char*)Qs + row * 256 + ((dcol << 1) ^ ((row & 7) << 4))) = val;
  }
  const f32x4 Z4 = {0.f, 0.f, 0.f, 0.f};
  f32x4 o[8];
  float mrun[4], lrun[4];
  #pragma unroll
  for (int i = 0; i < 8; ++i) o[i] = Z4;
  #pragma unroll
  for (int i = 0; i < 4; ++i) { mrun[i] = -1e30f; lrun[i] = 0.f; }
  const float sc = 0.08838834764831845f; // 1/sqrt(128)

  for (int kc = 0; kc <= qb; ++kc) {
    __syncthreads();
    #pragma unroll
    for (int c = 0; c < 4; ++c) {
      int fc = c * 256 + tid;
      int row = fc >> 4, dcol = (fc & 15) << 3;
      u16x8 val = *(const u16x8*)(kp + (size_t)(b * SEQ + kc * 64 + row) * ks + kvh * HDIM + dcol);
      *(u16x8*)((char*)Ks + row * 256 + ((dcol << 1) ^ ((row & 7) << 4))) = val;
    }
    #pragma unroll
    for (int c = 0; c < 4; ++c) {
      int fc = c * 256 + tid;
      int kr = fc >> 4, dc0 = (fc & 15) << 3;
      u16x8 val = *(const u16x8*)(vp + (size_t)(b * SEQ + kc * 64 + kr) * ks + kvh * HDIM + dc0);
      #pragma unroll
      for (int jj = 0; jj < 8; ++jj) {
        int dd = dc0 + jj;
        *(uint16_t*)((char*)Vt + dd * 128 + ((kr << 1) ^ ((dd & 7) << 4))) = val[jj];
      }
    }
    if (tid < 64) mkf[tid] = (maskp[b * SEQ + kc * 64 + tid] > 0) ? 1.f : 0.f;
    __syncthreads();
    f32x4 sf[4];
    #pragma unroll
    for (int i = 0; i < 4; ++i) sf[i] = Z4;
    #pragma unroll
    for (int ds = 0; ds < 4; ++ds) {
      int arow = wv * 16 + (l & 15);
      int acb = (ds * 64 + ((l >> 4) << 4)) ^ ((arow & 7) << 4);
      s16x8 af = *(const s16x8*)((const char*)Qs + arow * 256 + acb);
      #pragma unroll
      for (int ni = 0; ni < 4; ++ni) {
        int brow = ni * 16 + (l & 15);
        int bcb = (ds * 64 + ((l >> 4) << 4)) ^ ((brow & 7) << 4);
        s16x8 bf = *(const s16x8*)((const char*)Ks + brow * 256 + bcb);
        sf[ni] = mfma16(af, bf, sf[ni]);
      }
    }
    #pragma unroll
    for (int r = 0; r < 4; ++r) {
      int rloc = wv * 16 + ((l >> 4) << 2) + r;
      int qabs = qb * 64 + rloc;
      float vals[4];
      float vmax = -1e30f;
      #pragma unroll
      for (int ni = 0; ni < 4; ++ni) {
        int kl = ni * 16 + (l & 15);
        int kabs = kc * 64 + kl;
        bool ok = (kabs <= qabs) && (mkf[kl] > 0.5f);
        vals[ni] = ok ? sf[ni][r] * sc : -1e9f;
        vmax = fmaxf(vmax, vals[ni]);
      }
      #pragma unroll
      for (int off = 1; off < 16; off <<= 1) vmax = fmaxf(vmax, __shfl_xor(vmax, off));
      float mnew = fmaxf(mrun[r], vmax);
      float alpha = __expf(mrun[r] - mnew);
      mrun[r] = mnew;
      float ps = 0.f;
      #pragma unroll
      for (int ni = 0; ni < 4; ++ni) {
        float pe = __expf(vals[ni] - mnew);
        ps += pe;
        int colb = (ni * 16 + (l & 15)) << 1;
        *(uint16_t*)((char*)Ps + rloc * 128 + (colb ^ ((rloc & 7) << 4))) = f2bf(pe);
      }
      #pragma unroll
      for (int off = 1; off < 16; off <<= 1) ps += __shfl_xor(ps, off);
      lrun[r] = lrun[r] * alpha + ps;
      #pragma unroll
      for (int dn = 0; dn < 8; ++dn) o[dn][r] *= alpha;
    }
    __syncthreads();
    #pragma unroll
    for (int kk = 0; kk < 2; ++kk) {
      int prow = wv * 16 + (l & 15);
      int pcb = (kk * 64 + ((l >> 4) << 4)) ^ ((prow & 7) << 4);
      s16x8 pf = *(const s16x8*)((const char*)Ps + prow * 128 + pcb);
      #pragma unroll
      for (int dn = 0; dn < 8; ++dn) {
        int vrow = dn * 16 + (l & 15);
        int vcb = (kk * 64 + ((l >> 4) << 4)) ^ ((vrow & 7) << 4);
        s16x8 vf = *(const s16x8*)((const char*)Vt + vrow * 128 + vcb);
        o[dn] = mfma16(pf, vf, o[dn]);
      }
    }
  }
  #pragma unroll
  for (int r = 0; r < 4; ++r) {
    float inv = 1.f / lrun[r];
    int t = t0 + wv * 16 + ((l >> 4) << 2) + r;
    #pragma unroll
    for (int dn = 0; dn < 8; ++dn) {
      int dloc = dn * 16 + (l & 15);
      aop[(size_t)t * DMODEL + hh * HDIM + (dloc ^ ((t & 7) << 3))] = f2bf(o[dn][r] * inv);
    }
  }
}

// ------------------ last-token pool + normalize + project -----------------
__global__ __launch_bounds__(256) void k_pool(const float* __restrict__ h,
    const int* __restrict__ maskp, const float* __restrict__ dpw,
    const float* __restrict__ dpb, float* __restrict__ out)
{
  int i = blockIdx.x; // 0,1
  int tid = threadIdx.x, wv = tid >> 6, l = tid & 63;
  __shared__ float p1[4096];
  __shared__ float p2[4096];
  __shared__ float red[8];
  __shared__ int lastsh[2];
  if (tid < 2) {
    int b = i + tid * 2;
    int s = 0;
    for (int j = 0; j < 512; ++j) s += (maskp[b * 512 + j] > 0);
    lastsh[tid] = s - 1;
  }
  __syncthreads();
  const float* r1 = h + ((size_t)(i * 512 + lastsh[0])) * 4096;
  const float* r2 = h + ((size_t)((i + 2) * 512 + lastsh[1])) * 4096;
  float ss1 = 0.f, ss2 = 0.f;
  for (int d = tid; d < 4096; d += 256) {
    float a = r1[d], bb = r2[d];
    p1[d] = a; p2[d] = bb;
    ss1 += a * a; ss2 += bb * bb;
  }
  #pragma unroll
  for (int off = 1; off < 64; off <<= 1) {
    ss1 += __shfl_xor(ss1, off);
    ss2 += __shfl_xor(ss2, off);
  }
  if (l == 0) { red[wv] = ss1; red[4 + wv] = ss2; }
  __syncthreads();
  float n1 = fmaxf(sqrtf(red[0] + red[1] + red[2] + red[3]), 1e-12f);
  float n2 = fmaxf(sqrtf(red[4] + red[5] + red[6] + red[7]), 1e-12f);
  for (int oidx = wv; oidx < 50; oidx += 4) {
    float d1 = 0.f, d2 = 0.f;
    for (int d = l; d < 4096; d += 64) {
      float wval = dpw[(size_t)oidx * 4096 + d];
      d1 += wval * p1[d];
      d2 += wval * p2[d];
    }
    #pragma unroll
    for (int off = 1; off < 64; off <<= 1) {
      d1 += __shfl_xor(d1, off);
      d2 += __shfl_xor(d2, off);
    }
    if (l == 0) out[i * 50 + oidx] = (d1 / n1 + dpb[oidx]) * (d2 / n2 + dpb[oidx]);
  }
}

// ---------------------------------------------------------------------------
extern "C" void kernel_launch(void* const* d_in, const int* in_sizes, int n_in,
                              void* d_out, int out_size, void* d_ws, size_t ws_size,
                              hipStream_t stream) {
  const int*   ids   = (const int*)d_in[0];
  const int*   maskp = (const int*)d_in[1];
  const float* table = (const float*)d_in[2];
  const int* idxp[7];
  const float* amp[7];
  if (in_sizes[4] == in_sizes[3] / 64) {
    for (int i = 0; i < 7; ++i) {
      idxp[i] = (const int*)d_in[3 + 2 * i];
      amp[i]  = (const float*)d_in[4 + 2 * i];
    }
  } else {
    for (int i = 0; i < 7; ++i) {
      idxp[i] = (const int*)d_in[3 + i];
      amp[i]  = (const float*)d_in[10 + i];
    }
  }
  const float* rms1 = (const float*)d_in[17];
  const float* rms2 = (const float*)d_in[18];
  const float* dpw  = (const float*)d_in[19];
  const float* dpb  = (const float*)d_in[20];
  float* out = (float*)d_out;

  char* p = (char*)d_ws;
  uint16_t* wbuf  = (uint16_t*)p; p += (size_t)DFF * DMODEL * 2;   // 112 MiB
  float*    hbuf  = (float*)p;    p += (size_t)TOK * DMODEL * 4;   // 32 MiB
  uint16_t* rbuf  = (uint16_t*)p; p += (size_t)TOK * DMODEL * 2;
  uint16_t* qkv   = (uint16_t*)p; p += (size_t)TOK * 6144 * 2;     // 24 MiB
  uint16_t* aobuf = (uint16_t*)p; p += (size_t)TOK * DMODEL * 2;
  uint16_t* r2buf = (uint16_t*)p; p += (size_t)TOK * DMODEL * 2;
  uint16_t* gbuf  = (uint16_t*)p; p += (size_t)TOK * DFF * 2;      // 56 MiB
  uint16_t* hmbuf = (uint16_t*)p; p += (size_t)TOK * DFF * 2;      // 56 MiB

  uint16_t* qpart = qkv;
  uint16_t* kpart = qkv + 4096;
  uint16_t* vpart = qkv + 5120;

  // embed + rmsnorm1
  k_rms<<<TOK, 256, 0, stream>>>(ids, table, nullptr, rms1, hbuf, rbuf, 1);

  // fused QKV projection (W rows: q 0..4095, k 4096..5119, v 5120..6143)
  k_dequant<<<4096, 256, 0, stream>>>(idxp[0], amp[0], wbuf, DMODEL * DMODEL, DMODEL);
  k_dequant<<<2048, 256, 0, stream>>>(idxp[1], amp[1], wbuf + (size_t)4096 * DMODEL, DKVW * DMODEL, DMODEL);
  k_dequant<<<2048, 256, 0, stream>>>(idxp[2], amp[2], wbuf + (size_t)5120 * DMODEL, DKVW * DMODEL, DMODEL);
  k_gemm2<128, 0><<<dim3(48, 8), 512, 0, stream>>>(rbuf, wbuf, 6144, DMODEL, qkv, nullptr, nullptr);

  // RoPE (strided into qkv)
  k_rope2<<<(TOK * NHEAD * 64) / 256, 256, 0, stream>>>(qpart, NHEAD, 5, 6144);
  k_rope2<<<(TOK * NKVH * 64) / 256, 256, 0, stream>>>(kpart, NKVH, 3, 6144);

  // attention
  k_attn<<<dim3(SEQ / 64, NHEAD, 4), 256, 0, stream>>>(qpart, kpart, vpart, maskp, aobuf, 6144, 6144);

  // O projection, residual add into h
  k_dequant<<<4096, 256, 0, stream>>>(idxp[3], amp[3], wbuf, DMODEL * DMODEL, DMODEL);
  k_gemm2<128, 3><<<dim3(32, 8), 512, 0, stream>>>(aobuf, wbuf, DMODEL, DMODEL, nullptr, hbuf, nullptr);

  // rmsnorm2
  k_rms<<<TOK, 256, 0, stream>>>(nullptr, nullptr, hbuf, rms2, nullptr, r2buf, 0);

  // MLP
  k_dequant<<<4096, 256, 0, stream>>>(idxp[4], amp[4], wbuf, DFF * DMODEL, DMODEL);
  k_gemm2<256, 1><<<dim3(56, 8), 512, 0, stream>>>(r2buf, wbuf, DFF, DMODEL, gbuf, nullptr, nullptr);
  k_dequant<<<4096, 256, 0, stream>>>(idxp[5], amp[5], wbuf, DFF * DMODEL, DMODEL);
  k_gemm2<256, 2><<<dim3(56, 8), 512, 0, stream>>>(r2buf, wbuf, DFF, DMODEL, hmbuf, nullptr, gbuf);
  k_dequant<<<4096, 256, 0, stream>>>(idxp[6], amp[6], wbuf, DMODEL * DFF, DFF);
  k_gemm2<128, 3><<<dim3(32, 8), 512, 0, stream>>>(hmbuf, wbuf, DMODEL, DFF, nullptr, hbuf, nullptr);

  // pool + normalize + project + pairwise product
  k_pool<<<2, 256, 0, stream>>>(hbuf, maskp, dpw, dpb, out);
}

// Round 3
// 759.219 us; speedup vs baseline: 2.7512x; 2.6643x over previous
//
#include <hip/hip_runtime.h>
#include <stdint.h>
#include <math.h>

#define TOK 2048
#define DMODEL 4096
#define DFF 14336
#define SEQ 512

typedef float f32x4 __attribute__((ext_vector_type(4)));
typedef short s16x8 __attribute__((ext_vector_type(8)));
typedef unsigned short u16x8 __attribute__((ext_vector_type(8)));

__constant__ float NF4_TAB[16] = {
  -1.0f, -0.6961928009986877f, -0.5250730514526367f, -0.39491748809814453f,
  -0.28444138169288635f, -0.18477343022823334f, -0.09105003625154495f, 0.0f,
  0.07958029955625534f, 0.16093020141124725f, 0.24611230194568634f,
  0.33791524171829224f, 0.44070982933044434f, 0.5626170039176941f,
  0.7229568362236023f, 1.0f };

__device__ __forceinline__ uint16_t f2bf(float f) {
  union { float f; uint32_t u; } x; x.f = f;
  uint32_t r = (x.u + 0x7FFFu + ((x.u >> 16) & 1u)) >> 16;
  return (uint16_t)r;
}
__device__ __forceinline__ float bf2f(uint16_t u) {
  union { uint32_t u; float f; } x; x.u = ((uint32_t)u) << 16;
  return x.f;
}
__device__ __forceinline__ f32x4 mfma16(s16x8 a, s16x8 b, f32x4 c) {
  return __builtin_amdgcn_mfma_f32_16x16x32_bf16(a, b, c, 0, 0, 0);
}
__device__ __forceinline__ void gload_lds16(const void* g, void* l) {
  __builtin_amdgcn_global_load_lds(
    (const __attribute__((address_space(1))) unsigned int*)g,
    (__attribute__((address_space(3))) unsigned int*)l, 16, 0, 0);
}

// ---------------- last-token index per batch -------------------------------
__global__ __launch_bounds__(256) void k_last(const int* __restrict__ maskp,
                                              int* __restrict__ lastb)
{
  int wv = threadIdx.x >> 6, l = threadIdx.x & 63;
  int cnt = 0;
  for (int j = l; j < SEQ; j += 64) cnt += (maskp[wv * SEQ + j] > 0);
  #pragma unroll
  for (int off = 1; off < 64; off <<= 1) cnt += __shfl_xor(cnt, off);
  if (l == 0) lastb[wv] = cnt - 1;
}

// ---------------- NF4 dequant -> bf16, pre-swizzled for GEMM LDS tiles ----
__global__ __launch_bounds__(256) void k_dequant(const int* __restrict__ idx,
    const float* __restrict__ am, uint16_t* __restrict__ out, int nelems, int K)
{
  __shared__ float code[16];
  if (threadIdx.x < 16) code[threadIdx.x] = NF4_TAB[threadIdx.x];
  __syncthreads();
  int nch = nelems >> 3;
  int stride = gridDim.x * 256;
  for (int c = blockIdx.x * 256 + threadIdx.x; c < nch; c += stride) {
    int e = c << 3;
    int row = e / K;
    int kc = e - row * K;
    float a = am[c >> 3];
    int4 i0 = *(const int4*)(idx + e);
    int4 i1 = *(const int4*)(idx + e + 4);
    u16x8 pk;
    pk[0] = f2bf(code[i0.x] * a);
    pk[1] = f2bf(code[i0.y] * a);
    pk[2] = f2bf(code[i0.z] * a);
    pk[3] = f2bf(code[i0.w] * a);
    pk[4] = f2bf(code[i1.x] * a);
    pk[5] = f2bf(code[i1.y] * a);
    pk[6] = f2bf(code[i1.z] * a);
    pk[7] = f2bf(code[i1.w] * a);
    int dk = (kc & ~63) | (((((kc >> 3) & 7) ^ (row & 7))) << 3);
    *(u16x8*)(out + (size_t)row * K + dk) = pk;
  }
}

// ------------- fused embed-gather + RMSNorm -> bf16 swizzled ---------------
__global__ __launch_bounds__(256) void k_rms(const int* __restrict__ ids,
    const float* __restrict__ table, const float* __restrict__ w,
    uint16_t* __restrict__ r)
{
  int t = blockIdx.x, tid = threadIdx.x;
  int wv = tid >> 6, l = tid & 63;
  const float* src = table + (size_t)ids[t] * DMODEL;
  int d0 = tid * 16;
  float vals[16];
  float ss = 0.f;
  #pragma unroll
  for (int i = 0; i < 4; ++i) {
    float4 v4 = *(const float4*)(src + d0 + i * 4);
    vals[i*4+0] = v4.x; vals[i*4+1] = v4.y; vals[i*4+2] = v4.z; vals[i*4+3] = v4.w;
    ss += v4.x*v4.x + v4.y*v4.y + v4.z*v4.z + v4.w*v4.w;
  }
  #pragma unroll
  for (int off = 1; off < 64; off <<= 1) ss += __shfl_xor(ss, off);
  __shared__ float red[4];
  if (l == 0) red[wv] = ss;
  __syncthreads();
  float rs = rsqrtf((red[0]+red[1]+red[2]+red[3]) * (1.f/DMODEL) + 1e-5f);
  #pragma unroll
  for (int cth = 0; cth < 2; ++cth) {
    int dd = d0 + cth * 8;
    u16x8 pk;
    #pragma unroll
    for (int j = 0; j < 8; ++j) pk[j] = f2bf(vals[cth*8+j] * rs * w[dd + j]);
    int dsw = (dd & ~63) | (((((dd >> 3) & 7) ^ (t & 7))) << 3);
    *(u16x8*)(r + (size_t)t * DMODEL + dsw) = pk;
  }
}

// ======================= 8-phase 256x256 split-K GEMM ======================
// kv = rbuf(2048x4096 swz) @ wbuf(2048x4096 swz)^T, K-chunk 1024 per z.
// Writes f32 partials pout[z][2048][2048].
__global__ __launch_bounds__(512, 2) void k_gemmkv(
    const uint16_t* __restrict__ A, const uint16_t* __restrict__ W,
    float* __restrict__ pout)
{
  constexpr int K = 4096;
  constexpr int NT = 16;
  __shared__ __align__(1024) uint16_t As_[2 * 256 * 64];
  __shared__ __align__(1024) uint16_t Bs_[2 * 256 * 64];
  const int tid = threadIdx.x;
  const int wid = tid >> 6, l = tid & 63;
  const int wr = wid >> 2, wc = wid & 3;
  const int n0 = blockIdx.x * 256, m0 = blockIdx.y * 256;
  const size_t kbase = blockIdx.z * 1024;
  const int lrow = l >> 3, lcb = (l & 7) * 16;

  auto stA = [&](int t, int h) {
    int ta = (t < NT) ? t : (t - NT);
    const char* g = (const char*)A +
        ((size_t)(m0 + h * 128 + wid * 16 + lrow) * K + kbase + ta * 64) * 2 + lcb;
    char* s = (char*)As_ + (t & 1) * 32768 + h * 16384 + wid * 2048;
    gload_lds16(g, s);
    gload_lds16(g + (size_t)8 * K * 2, s + 1024);
  };
  auto stB = [&](int t, int h) {
    int ta = (t < NT) ? t : (t - NT);
    const char* g = (const char*)W +
        ((size_t)(n0 + h * 128 + wid * 16 + lrow) * K + kbase + ta * 64) * 2 + lcb;
    char* s = (char*)Bs_ + (t & 1) * 32768 + h * 16384 + wid * 2048;
    gload_lds16(g, s);
    gload_lds16(g + (size_t)8 * K * 2, s + 1024);
  };

  const int cb0 = (((l >> 4) << 4)) ^ ((l & 7) << 4);
  const int cb1 = (64 + ((l >> 4) << 4)) ^ ((l & 7) << 4);

  const f32x4 Z4 = {0.f, 0.f, 0.f, 0.f};
  f32x4 acc[8][4];
  #pragma unroll
  for (int i = 0; i < 8; ++i)
    #pragma unroll
    for (int j = 0; j < 4; ++j) acc[i][j] = Z4;
  s16x8 bfr[4][2];

#define VMW asm volatile("s_waitcnt vmcnt(6)" ::: "memory")
#define PHASE(DB, Q, READB, STG) {                                          \
    const char* abase = (const char*)As_ + (DB) * 32768;                    \
    s16x8 af[2][2];                                                         \
    _Pragma("unroll") for (int mm = 0; mm < 2; ++mm) {                      \
      int arow = ((2 * (2 * (Q) + mm) + wr) * 16 + (l & 15)) * 128;         \
      af[mm][0] = *(const s16x8*)(abase + arow + cb0);                      \
      af[mm][1] = *(const s16x8*)(abase + arow + cb1);                      \
    }                                                                       \
    if (READB) {                                                            \
      const char* bbase = (const char*)Bs_ + (DB) * 32768;                  \
      _Pragma("unroll") for (int nn = 0; nn < 4; ++nn) {                    \
        int brow = (wc * 64 + nn * 16 + (l & 15)) * 128;                    \
        bfr[nn][0] = *(const s16x8*)(bbase + brow + cb0);                   \
        bfr[nn][1] = *(const s16x8*)(bbase + brow + cb1);                   \
      }                                                                     \
    }                                                                       \
    STG;                                                                    \
    __builtin_amdgcn_s_barrier();                                           \
    asm volatile("s_waitcnt lgkmcnt(0)" ::: "memory");                      \
    __builtin_amdgcn_sched_barrier(0);                                      \
    __builtin_amdgcn_s_setprio(1);                                          \
    _Pragma("unroll") for (int mm = 0; mm < 2; ++mm)                        \
      _Pragma("unroll") for (int nn = 0; nn < 4; ++nn) {                    \
        acc[2 * (Q) + mm][nn] = mfma16(af[mm][0], bfr[nn][0], acc[2 * (Q) + mm][nn]); \
        acc[2 * (Q) + mm][nn] = mfma16(af[mm][1], bfr[nn][1], acc[2 * (Q) + mm][nn]); \
      }                                                                     \
    __builtin_amdgcn_s_setprio(0);                                          \
    __builtin_amdgcn_s_barrier();                                           \
  }

  stB(0, 0); stA(0, 0); stB(0, 1); stA(0, 1);
  stB(1, 0); stA(1, 0); stB(1, 1);
  VMW;
  __builtin_amdgcn_s_barrier();

  for (int it = 0; it < NT / 2; ++it) {
    int t0 = 2 * it, t1 = t0 + 1;
    PHASE(0, 0, 1, stA(t1, 1));
    PHASE(0, 1, 0, stB(t0 + 2, 0));
    PHASE(0, 2, 0, stA(t0 + 2, 0));
    PHASE(0, 3, 0, { stB(t0 + 2, 1); VMW; });
    PHASE(1, 0, 1, stA(t0 + 2, 1));
    PHASE(1, 1, 0, stB(t1 + 2, 0));
    PHASE(1, 2, 0, stA(t1 + 2, 0));
    PHASE(1, 3, 0, { stB(t1 + 2, 1); VMW; });
  }
  asm volatile("s_waitcnt vmcnt(0)" ::: "memory");
  __builtin_amdgcn_s_barrier();
#undef PHASE
#undef VMW

  float* po = pout + (size_t)blockIdx.z * 2048 * 2048;
  #pragma unroll
  for (int mf = 0; mf < 8; ++mf)
    #pragma unroll
    for (int nf = 0; nf < 4; ++nf)
      #pragma unroll
      for (int r = 0; r < 4; ++r) {
        int row = m0 + (2 * mf + wr) * 16 + ((l >> 4) << 2) + r;
        int col = n0 + wc * 64 + nf * 16 + (l & 15);
        po[(size_t)row * 2048 + col] = acc[mf][nf][r];
      }
}

// -------- reduce split-K partials + RoPE(k) -> kvbuf bf16 [2048][2048] -----
__global__ __launch_bounds__(256) void k_redrope(const float* __restrict__ p,
    uint16_t* __restrict__ kv)
{
  int t = blockIdx.x, tid = threadIdx.x;
  const size_t zs = (size_t)2048 * 2048;
  auto sum4 = [&](int c) -> float {
    size_t o = (size_t)t * 2048 + c;
    return p[o] + p[o + zs] + p[o + 2 * zs] + p[o + 3 * zs];
  };
  float pos = (float)(t & (SEQ - 1));
  for (int pi = tid; pi < 512; pi += 256) {
    int hh = pi >> 6, j = pi & 63;
    int c1 = hh * 128 + j, c2 = c1 + 64;
    float s1 = sum4(c1), s2 = sum4(c2);
    float f = pos * expf(-(float)j * 0.14391156831212787f);
    float sn, cs;
    sincosf(f, &sn, &cs);
    kv[(size_t)t * 2048 + c1] = f2bf(s1 * cs - s2 * sn);
    kv[(size_t)t * 2048 + c2] = f2bf(s2 * cs + s1 * sn);
  }
  for (int c = 1024 + tid; c < 2048; c += 256)
    kv[(size_t)t * 2048 + c] = f2bf(sum4(c));
}

// -------- gather r (rms1 out) at last tokens, unswizzle -> f32 [4][4096] ---
__global__ __launch_bounds__(256) void k_prep_r4(const uint16_t* __restrict__ rbuf,
    const int* __restrict__ lastb, float* __restrict__ r4f)
{
  int r = blockIdx.x;
  int t = r * SEQ + lastb[r];
  const uint16_t* src = rbuf + (size_t)t * DMODEL;
  for (int k = threadIdx.x * 8; k < DMODEL; k += 2048) {
    int so = (k & ~63) | (((((k >> 3) & 7) ^ (t & 7))) << 3);
    u16x8 v = *(const u16x8*)(src + so);
    #pragma unroll
    for (int j = 0; j < 8; ++j) r4f[r * DMODEL + k + j] = bf2f(v[j]);
  }
}

// -------- 4-row fused dequant GEMV: out[r][n] = (base?) + a4[r] . W[n] -----
// MODE 0: plain f32 store. MODE 1: out = embed_base + dot (f32).
template<int MODE>
__global__ __launch_bounds__(256) void k_gemv4(const int* __restrict__ idx,
    const float* __restrict__ am, const float* __restrict__ a4,
    float* __restrict__ out, const float* __restrict__ table,
    const int* __restrict__ ids, const int* __restrict__ lastb)
{
  __shared__ float As[4 * 4096];
  __shared__ float code[16];
  if (threadIdx.x < 16) code[threadIdx.x] = NF4_TAB[threadIdx.x];
  for (int i = threadIdx.x * 4; i < 4 * 4096; i += 1024)
    *(float4*)(As + i) = *(const float4*)(a4 + i);
  __syncthreads();
  int wv = threadIdx.x >> 6, l = threadIdx.x & 63;
  int lhi = l >> 4;
  for (int n = blockIdx.x * 4 + wv; n < 4096; n += gridDim.x * 4) {
    const int4* ip = (const int4*)(idx + (size_t)n * 4096);
    const float* ap = am + (size_t)n * 64;
    float a0 = 0.f, a1 = 0.f, a2 = 0.f, a3 = 0.f;
    #pragma unroll
    for (int kk = 0; kk < 16; ++kk) {
      int4 iv = ip[kk * 64 + l];
      float sc = ap[kk * 4 + lhi];
      float w0 = code[iv.x] * sc, w1 = code[iv.y] * sc;
      float w2 = code[iv.z] * sc, w3 = code[iv.w] * sc;
      const float* A0 = As + kk * 256 + l * 4;
      f32x4 v0 = *(const f32x4*)A0;
      f32x4 v1 = *(const f32x4*)(A0 + 4096);
      f32x4 v2 = *(const f32x4*)(A0 + 8192);
      f32x4 v3 = *(const f32x4*)(A0 + 12288);
      a0 = fmaf(w0, v0[0], fmaf(w1, v0[1], fmaf(w2, v0[2], fmaf(w3, v0[3], a0))));
      a1 = fmaf(w0, v1[0], fmaf(w1, v1[1], fmaf(w2, v1[2], fmaf(w3, v1[3], a1))));
      a2 = fmaf(w0, v2[0], fmaf(w1, v2[1], fmaf(w2, v2[2], fmaf(w3, v2[3], a2))));
      a3 = fmaf(w0, v3[0], fmaf(w1, v3[1], fmaf(w2, v3[2], fmaf(w3, v3[3], a3))));
    }
    #pragma unroll
    for (int off = 1; off < 64; off <<= 1) {
      a0 += __shfl_xor(a0, off); a1 += __shfl_xor(a1, off);
      a2 += __shfl_xor(a2, off); a3 += __shfl_xor(a3, off);
    }
    if (l == 0) {
      float av[4] = {a0, a1, a2, a3};
      #pragma unroll
      for (int r = 0; r < 4; ++r) {
        float base = 0.f;
        if (MODE == 1)
          base = table[(size_t)ids[r * SEQ + lastb[r]] * DMODEL + n];
        out[r * 4096 + n] = base + av[r];
      }
    }
  }
}

// -------- fused gate+up 4-row GEMV: hm[r][n] = silu(g)*u -------------------
__global__ __launch_bounds__(256) void k_gemv_gu(const int* __restrict__ idxg,
    const float* __restrict__ amg, const int* __restrict__ idxu,
    const float* __restrict__ amu, const float* __restrict__ a4,
    uint16_t* __restrict__ hm)
{
  __shared__ float As[4 * 4096];
  __shared__ float code[16];
  if (threadIdx.x < 16) code[threadIdx.x] = NF4_TAB[threadIdx.x];
  for (int i = threadIdx.x * 4; i < 4 * 4096; i += 1024)
    *(float4*)(As + i) = *(const float4*)(a4 + i);
  __syncthreads();
  int wv = threadIdx.x >> 6, l = threadIdx.x & 63;
  int lhi = l >> 4;
  for (int n = blockIdx.x * 4 + wv; n < DFF; n += gridDim.x * 4) {
    const int4* ipg = (const int4*)(idxg + (size_t)n * 4096);
    const int4* ipu = (const int4*)(idxu + (size_t)n * 4096);
    const float* apg = amg + (size_t)n * 64;
    const float* apu = amu + (size_t)n * 64;
    float g0 = 0.f, g1 = 0.f, g2 = 0.f, g3 = 0.f;
    float u0 = 0.f, u1 = 0.f, u2 = 0.f, u3 = 0.f;
    #pragma unroll 8
    for (int kk = 0; kk < 16; ++kk) {
      int4 ig = ipg[kk * 64 + l];
      int4 iu = ipu[kk * 64 + l];
      float sg = apg[kk * 4 + lhi];
      float su = apu[kk * 4 + lhi];
      float wg0 = code[ig.x] * sg, wg1 = code[ig.y] * sg;
      float wg2 = code[ig.z] * sg, wg3 = code[ig.w] * sg;
      float wu0 = code[iu.x] * su, wu1 = code[iu.y] * su;
      float wu2 = code[iu.z] * su, wu3 = code[iu.w] * su;
      const float* A0 = As + kk * 256 + l * 4;
      f32x4 v0 = *(const f32x4*)A0;
      f32x4 v1 = *(const f32x4*)(A0 + 4096);
      f32x4 v2 = *(const f32x4*)(A0 + 8192);
      f32x4 v3 = *(const f32x4*)(A0 + 12288);
      g0 = fmaf(wg0, v0[0], fmaf(wg1, v0[1], fmaf(wg2, v0[2], fmaf(wg3, v0[3], g0))));
      g1 = fmaf(wg0, v1[0], fmaf(wg1, v1[1], fmaf(wg2, v1[2], fmaf(wg3, v1[3], g1))));
      g2 = fmaf(wg0, v2[0], fmaf(wg1, v2[1], fmaf(wg2, v2[2], fmaf(wg3, v2[3], g2))));
      g3 = fmaf(wg0, v3[0], fmaf(wg1, v3[1], fmaf(wg2, v3[2], fmaf(wg3, v3[3], g3))));
      u0 = fmaf(wu0, v0[0], fmaf(wu1, v0[1], fmaf(wu2, v0[2], fmaf(wu3, v0[3], u0))));
      u1 = fmaf(wu0, v1[0], fmaf(wu1, v1[1], fmaf(wu2, v1[2], fmaf(wu3, v1[3], u1))));
      u2 = fmaf(wu0, v2[0], fmaf(wu1, v2[1], fmaf(wu2, v2[2], fmaf(wu3, v2[3], u2))));
      u3 = fmaf(wu0, v3[0], fmaf(wu1, v3[1], fmaf(wu2, v3[2], fmaf(wu3, v3[3], u3))));
    }
    #pragma unroll
    for (int off = 1; off < 64; off <<= 1) {
      g0 += __shfl_xor(g0, off); g1 += __shfl_xor(g1, off);
      g2 += __shfl_xor(g2, off); g3 += __shfl_xor(g3, off);
      u0 += __shfl_xor(u0, off); u1 += __shfl_xor(u1, off);
      u2 += __shfl_xor(u2, off); u3 += __shfl_xor(u3, off);
    }
    if (l == 0) {
      float gv[4] = {g0, g1, g2, g3};
      float uv[4] = {u0, u1, u2, u3};
      #pragma unroll
      for (int r = 0; r < 4; ++r) {
        float g = gv[r];
        hm[(size_t)r * DFF + n] = f2bf((g / (1.f + __expf(-g))) * uv[r]);
      }
    }
  }
}

// -------- down 4-row GEMV (K=14336, a4 bf16 in LDS): h4f = h4 + dot --------
__global__ __launch_bounds__(256) void k_gemv_down(const int* __restrict__ idx,
    const float* __restrict__ am, const uint16_t* __restrict__ hm,
    const float* __restrict__ h4, float* __restrict__ h4f)
{
  __shared__ uint16_t As[4 * 14336];
  __shared__ float code[16];
  if (threadIdx.x < 16) code[threadIdx.x] = NF4_TAB[threadIdx.x];
  for (int i = threadIdx.x * 8; i < 4 * 14336; i += 2048)
    *(u16x8*)(As + i) = *(const u16x8*)(hm + i);
  __syncthreads();
  int wv = threadIdx.x >> 6, l = threadIdx.x & 63;
  int lhi = l >> 4;
  for (int n = blockIdx.x * 4 + wv; n < 4096; n += gridDim.x * 4) {
    const int4* ip = (const int4*)(idx + (size_t)n * 14336);
    const float* ap = am + (size_t)n * 224;
    float a0 = 0.f, a1 = 0.f, a2 = 0.f, a3 = 0.f;
    #pragma unroll 8
    for (int kk = 0; kk < 56; ++kk) {
      int4 iv = ip[kk * 64 + l];
      float sc = ap[kk * 4 + lhi];
      float w0 = code[iv.x] * sc, w1 = code[iv.y] * sc;
      float w2 = code[iv.z] * sc, w3 = code[iv.w] * sc;
      int k0 = kk * 256 + l * 4;
      const uint16_t* B0 = As + k0;
      #pragma unroll
      for (int r = 0; r < 4; ++r) {
        u16x8 hv8;
        *(uint2*)&hv8 = *(const uint2*)(B0 + r * 14336);
        float x0 = bf2f(hv8[0]), x1 = bf2f(hv8[1]);
        float x2 = bf2f(hv8[2]), x3 = bf2f(hv8[3]);
        float t = fmaf(w0, x0, fmaf(w1, x1, fmaf(w2, x2, w3 * x3)));
        if (r == 0) a0 += t; else if (r == 1) a1 += t;
        else if (r == 2) a2 += t; else a3 += t;
      }
    }
    #pragma unroll
    for (int off = 1; off < 64; off <<= 1) {
      a0 += __shfl_xor(a0, off); a1 += __shfl_xor(a1, off);
      a2 += __shfl_xor(a2, off); a3 += __shfl_xor(a3, off);
    }
    if (l == 0) {
      float av[4] = {a0, a1, a2, a3};
      #pragma unroll
      for (int r = 0; r < 4; ++r)
        h4f[r * 4096 + n] = h4[r * 4096 + n] + av[r];
    }
  }
}

// -------- 4-query attention (rope on q inside), f32 ------------------------
__global__ __launch_bounds__(256) void k_attn4(const float* __restrict__ q4,
    const uint16_t* __restrict__ kv, const int* __restrict__ maskp,
    const int* __restrict__ lastb, float* __restrict__ ao4)
{
  int hh = blockIdx.x, b = blockIdx.y;
  int kvh = hh >> 2;
  int tid = threadIdx.x;
  __shared__ float qs[128];
  __shared__ float sarr[512];
  __shared__ float red[256];
  __shared__ float oacc[2][128];
  int last = lastb[b];
  if (tid < 128) {
    int d = tid, j = d & 63;
    float f = (float)last * expf(-(float)j * 0.14391156831212787f);
    float sn, cs;
    sincosf(f, &sn, &cs);
    const float* q = q4 + b * 4096 + hh * 128;
    float v = (d < 64) ? (q[d] * cs - q[d + 64] * sn)
                       : (q[d] * cs + q[d - 64] * sn);
    qs[d] = v * 0.08838834764831845f;
  }
  __syncthreads();
  float sl[2];
  #pragma unroll
  for (int h2 = 0; h2 < 2; ++h2) {
    int jj = tid + h2 * 256;
    bool valid = (jj <= last) && (maskp[b * SEQ + jj] > 0);
    float s = -1e9f;
    if (valid) {
      s = 0.f;
      const uint16_t* kp = kv + ((size_t)(b * SEQ + jj)) * 2048 + kvh * 128;
      #pragma unroll
      for (int c = 0; c < 16; ++c) {
        u16x8 kvv = *(const u16x8*)(kp + c * 8);
        #pragma unroll
        for (int e = 0; e < 8; ++e)
          s = fmaf(qs[c * 8 + e], bf2f(kvv[e]), s);
      }
    }
    sarr[jj] = s;
    sl[h2] = s;
  }
  // block max
  red[tid] = fmaxf(sl[0], sl[1]);
  __syncthreads();
  for (int s = 128; s > 0; s >>= 1) {
    if (tid < s) red[tid] = fmaxf(red[tid], red[tid + s]);
    __syncthreads();
  }
  float m = red[0];
  __syncthreads();
  float ps = 0.f;
  #pragma unroll
  for (int h2 = 0; h2 < 2; ++h2) {
    int jj = tid + h2 * 256;
    float pe = __expf(sarr[jj] - m);
    ps += pe;
    sarr[jj] = pe;
  }
  red[tid] = ps;
  __syncthreads();
  for (int s = 128; s > 0; s >>= 1) {
    if (tid < s) red[tid] += red[tid + s];
    __syncthreads();
  }
  float inv = 1.f / red[0];
  __syncthreads();
  // o = sum p_j v_j
  int half = tid >> 7, d = tid & 127;
  float acc = 0.f;
  const uint16_t* vp = kv + ((size_t)(b * SEQ + half * 256)) * 2048 + 1024 + kvh * 128 + d;
  for (int j = 0; j < 256; ++j)
    acc = fmaf(sarr[half * 256 + j], bf2f(vp[(size_t)j * 2048]), acc);
  oacc[half][d] = acc;
  __syncthreads();
  if (tid < 128)
    ao4[b * 4096 + hh * 128 + tid] = (oacc[0][tid] + oacc[1][tid]) * inv;
}

// -------- rms2 on 4 rows ----------------------------------------------------
__global__ __launch_bounds__(256) void k_rms2(const float* __restrict__ h4,
    const float* __restrict__ w, float* __restrict__ r2f)
{
  int b = blockIdx.x, tid = threadIdx.x;
  int wv = tid >> 6, l = tid & 63;
  int d0 = tid * 16;
  const float* src = h4 + b * 4096;
  float vals[16];
  float ss = 0.f;
  #pragma unroll
  for (int i = 0; i < 4; ++i) {
    float4 v4 = *(const float4*)(src + d0 + i * 4);
    vals[i*4+0] = v4.x; vals[i*4+1] = v4.y; vals[i*4+2] = v4.z; vals[i*4+3] = v4.w;
    ss += v4.x*v4.x + v4.y*v4.y + v4.z*v4.z + v4.w*v4.w;
  }
  #pragma unroll
  for (int off = 1; off < 64; off <<= 1) ss += __shfl_xor(ss, off);
  __shared__ float red[4];
  if (l == 0) red[wv] = ss;
  __syncthreads();
  float rs = rsqrtf((red[0]+red[1]+red[2]+red[3]) * (1.f/4096.f) + 1e-5f);
  #pragma unroll
  for (int i = 0; i < 16; ++i)
    r2f[b * 4096 + d0 + i] = vals[i] * rs * w[d0 + i];
}

// -------- pool: normalize rows, project, pairwise product ------------------
__global__ __launch_bounds__(256) void k_pool2(const float* __restrict__ h4f,
    const float* __restrict__ dpw, const float* __restrict__ dpb,
    float* __restrict__ out)
{
  int tid = threadIdx.x, wv = tid >> 6, l = tid & 63;
  __shared__ float norms[4];
  __shared__ float embv[4][52];
  float ss = 0.f;
  const float* row = h4f + wv * 4096;
  for (int d = l * 4; d < 4096; d += 256) {
    float4 v = *(const float4*)(row + d);
    ss += v.x*v.x + v.y*v.y + v.z*v.z + v.w*v.w;
  }
  #pragma unroll
  for (int off = 1; off < 64; off <<= 1) ss += __shfl_xor(ss, off);
  if (l == 0) norms[wv] = fmaxf(sqrtf(ss), 1e-12f);
  __syncthreads();
  for (int o = 0; o < 50; ++o) {
    float d1 = 0.f;
    const float* wrow = dpw + (size_t)o * 4096;
    for (int d = l * 4; d < 4096; d += 256) {
      float4 v = *(const float4*)(row + d);
      float4 u = *(const float4*)(wrow + d);
      d1 += v.x*u.x + v.y*u.y + v.z*u.z + v.w*u.w;
    }
    #pragma unroll
    for (int off = 1; off < 64; off <<= 1) d1 += __shfl_xor(d1, off);
    if (l == 0) embv[wv][o] = d1 / norms[wv] + dpb[o];
  }
  __syncthreads();
  if (tid < 100) {
    int i = tid / 50, o = tid % 50;
    out[tid] = embv[i][o] * embv[i + 2][o];
  }
}

// ---------------------------------------------------------------------------
extern "C" void kernel_launch(void* const* d_in, const int* in_sizes, int n_in,
                              void* d_out, int out_size, void* d_ws, size_t ws_size,
                              hipStream_t stream) {
  const int*   ids   = (const int*)d_in[0];
  const int*   maskp = (const int*)d_in[1];
  const float* table = (const float*)d_in[2];
  const int* idxp[7];
  const float* amp[7];
  if (in_sizes[4] == in_sizes[3] / 64) {
    for (int i = 0; i < 7; ++i) {
      idxp[i] = (const int*)d_in[3 + 2 * i];
      amp[i]  = (const float*)d_in[4 + 2 * i];
    }
  } else {
    for (int i = 0; i < 7; ++i) {
      idxp[i] = (const int*)d_in[3 + i];
      amp[i]  = (const float*)d_in[10 + i];
    }
  }
  const float* rms1 = (const float*)d_in[17];
  const float* rms2w = (const float*)d_in[18];
  const float* dpw  = (const float*)d_in[19];
  const float* dpb  = (const float*)d_in[20];
  float* out = (float*)d_out;

  char* p = (char*)d_ws;
  int*      lastb = (int*)p;      p += 256;
  float*    r4f   = (float*)p;    p += 4 * 4096 * 4;
  float*    q4    = (float*)p;    p += 4 * 4096 * 4;
  float*    ao4   = (float*)p;    p += 4 * 4096 * 4;
  float*    h4    = (float*)p;    p += 4 * 4096 * 4;
  float*    r2f   = (float*)p;    p += 4 * 4096 * 4;
  float*    h4f   = (float*)p;    p += 4 * 4096 * 4;
  uint16_t* hm4   = (uint16_t*)p; p += 4 * DFF * 2 + 512;
  uint16_t* kvbuf = (uint16_t*)p; p += (size_t)TOK * 2048 * 2;       // 8 MiB
  uint16_t* rbuf  = (uint16_t*)p; p += (size_t)TOK * DMODEL * 2;     // 16 MiB
  uint16_t* wbuf  = (uint16_t*)p; p += (size_t)2048 * DMODEL * 2;    // 16 MiB
  float*    pbuf  = (float*)p;    p += (size_t)4 * 2048 * 2048 * 4;  // 64 MiB

  k_last<<<1, 256, 0, stream>>>(maskp, lastb);
  k_rms<<<TOK, 256, 0, stream>>>(ids, table, rms1, rbuf);

  // K,V projections (all tokens) via MFMA split-K GEMM
  k_dequant<<<2048, 256, 0, stream>>>(idxp[1], amp[1], wbuf, 1024 * DMODEL, DMODEL);
  k_dequant<<<2048, 256, 0, stream>>>(idxp[2], amp[2], wbuf + (size_t)1024 * DMODEL, 1024 * DMODEL, DMODEL);
  k_gemmkv<<<dim3(8, 8, 4), 512, 0, stream>>>(rbuf, wbuf, pbuf);
  k_redrope<<<TOK, 256, 0, stream>>>(pbuf, kvbuf);

  // Q at the 4 last tokens
  k_prep_r4<<<4, 256, 0, stream>>>(rbuf, lastb, r4f);
  k_gemv4<0><<<512, 256, 0, stream>>>(idxp[0], amp[0], r4f, q4, nullptr, nullptr, nullptr);

  // attention for 4 queries
  k_attn4<<<dim3(32, 4), 256, 0, stream>>>(q4, kvbuf, maskp, lastb, ao4);

  // O projection + embed residual -> h4
  k_gemv4<1><<<512, 256, 0, stream>>>(idxp[3], amp[3], ao4, h4, table, ids, lastb);

  // rms2 + MLP on 4 rows
  k_rms2<<<4, 256, 0, stream>>>(h4, rms2w, r2f);
  k_gemv_gu<<<448, 256, 0, stream>>>(idxp[4], amp[4], idxp[5], amp[5], r2f, hm4);
  k_gemv_down<<<256, 256, 0, stream>>>(idxp[6], amp[6], hm4, h4, h4f);

  // pool + normalize + project + pairwise product
  k_pool2<<<1, 256, 0, stream>>>(h4f, dpw, dpb, out);
}

// Round 4
// 411.791 us; speedup vs baseline: 5.0724x; 1.8437x over previous
//
#include <hip/hip_runtime.h>
#include <stdint.h>
#include <math.h>

#define TOK 2048
#define DMODEL 4096
#define DFF 14336
#define SEQ 512

typedef float f32x4 __attribute__((ext_vector_type(4)));
typedef short s16x8 __attribute__((ext_vector_type(8)));
typedef unsigned short u16x8 __attribute__((ext_vector_type(8)));

__constant__ float NF4_TAB[16] = {
  -1.0f, -0.6961928009986877f, -0.5250730514526367f, -0.39491748809814453f,
  -0.28444138169288635f, -0.18477343022823334f, -0.09105003625154495f, 0.0f,
  0.07958029955625534f, 0.16093020141124725f, 0.24611230194568634f,
  0.33791524171829224f, 0.44070982933044434f, 0.5626170039176941f,
  0.7229568362236023f, 1.0f };

__device__ __forceinline__ uint16_t f2bf(float f) {
  union { float f; uint32_t u; } x; x.f = f;
  uint32_t r = (x.u + 0x7FFFu + ((x.u >> 16) & 1u)) >> 16;
  return (uint16_t)r;
}
__device__ __forceinline__ float bf2f(uint16_t u) {
  union { uint32_t u; float f; } x; x.u = ((uint32_t)u) << 16;
  return x.f;
}
__device__ __forceinline__ f32x4 mfma16(s16x8 a, s16x8 b, f32x4 c) {
  return __builtin_amdgcn_mfma_f32_16x16x32_bf16(a, b, c, 0, 0, 0);
}
__device__ __forceinline__ void gload_lds16(const void* g, void* l) {
  __builtin_amdgcn_global_load_lds(
    (const __attribute__((address_space(1))) unsigned int*)g,
    (__attribute__((address_space(3))) unsigned int*)l, 16, 0, 0);
}

// ---------------- last-token index per batch -------------------------------
__global__ __launch_bounds__(256) void k_last(const int* __restrict__ maskp,
                                              int* __restrict__ lastb)
{
  int wv = threadIdx.x >> 6, l = threadIdx.x & 63;
  int cnt = 0;
  for (int j = l; j < SEQ; j += 64) cnt += (maskp[wv * SEQ + j] > 0);
  #pragma unroll
  for (int off = 1; off < 64; off <<= 1) cnt += __shfl_xor(cnt, off);
  if (l == 0) lastb[wv] = cnt - 1;
}

// ---------------- NF4 dequant -> bf16, pre-swizzled for GEMM LDS tiles ----
__global__ __launch_bounds__(256) void k_dequant(const int* __restrict__ idx,
    const float* __restrict__ am, uint16_t* __restrict__ out, int nelems, int K)
{
  __shared__ float code[16];
  if (threadIdx.x < 16) code[threadIdx.x] = NF4_TAB[threadIdx.x];
  __syncthreads();
  int nch = nelems >> 3;
  int stride = gridDim.x * 256;
  for (int c = blockIdx.x * 256 + threadIdx.x; c < nch; c += stride) {
    int e = c << 3;
    int row = e / K;
    int kc = e - row * K;
    float a = am[c >> 3];
    int4 i0 = *(const int4*)(idx + e);
    int4 i1 = *(const int4*)(idx + e + 4);
    u16x8 pk;
    pk[0] = f2bf(code[i0.x] * a);
    pk[1] = f2bf(code[i0.y] * a);
    pk[2] = f2bf(code[i0.z] * a);
    pk[3] = f2bf(code[i0.w] * a);
    pk[4] = f2bf(code[i1.x] * a);
    pk[5] = f2bf(code[i1.y] * a);
    pk[6] = f2bf(code[i1.z] * a);
    pk[7] = f2bf(code[i1.w] * a);
    int dk = (kc & ~63) | (((((kc >> 3) & 7) ^ (row & 7))) << 3);
    *(u16x8*)(out + (size_t)row * K + dk) = pk;
  }
}

// ------------- fused embed-gather + RMSNorm -> bf16 swizzled ---------------
__global__ __launch_bounds__(256) void k_rms(const int* __restrict__ ids,
    const float* __restrict__ table, const float* __restrict__ w,
    uint16_t* __restrict__ r)
{
  int t = blockIdx.x, tid = threadIdx.x;
  int wv = tid >> 6, l = tid & 63;
  const float* src = table + (size_t)ids[t] * DMODEL;
  int d0 = tid * 16;
  float vals[16];
  float ss = 0.f;
  #pragma unroll
  for (int i = 0; i < 4; ++i) {
    float4 v4 = *(const float4*)(src + d0 + i * 4);
    vals[i*4+0] = v4.x; vals[i*4+1] = v4.y; vals[i*4+2] = v4.z; vals[i*4+3] = v4.w;
    ss += v4.x*v4.x + v4.y*v4.y + v4.z*v4.z + v4.w*v4.w;
  }
  #pragma unroll
  for (int off = 1; off < 64; off <<= 1) ss += __shfl_xor(ss, off);
  __shared__ float red[4];
  if (l == 0) red[wv] = ss;
  __syncthreads();
  float rs = rsqrtf((red[0]+red[1]+red[2]+red[3]) * (1.f/DMODEL) + 1e-5f);
  #pragma unroll
  for (int cth = 0; cth < 2; ++cth) {
    int dd = d0 + cth * 8;
    u16x8 pk;
    #pragma unroll
    for (int j = 0; j < 8; ++j) pk[j] = f2bf(vals[cth*8+j] * rs * w[dd + j]);
    int dsw = (dd & ~63) | (((((dd >> 3) & 7) ^ (t & 7))) << 3);
    *(u16x8*)(r + (size_t)t * DMODEL + dsw) = pk;
  }
}

// ======================= 8-phase 256x256 split-K GEMM ======================
__global__ __launch_bounds__(512, 2) void k_gemmkv(
    const uint16_t* __restrict__ A, const uint16_t* __restrict__ W,
    float* __restrict__ pout)
{
  constexpr int K = 4096;
  constexpr int NT = 16;
  __shared__ __align__(1024) uint16_t As_[2 * 256 * 64];
  __shared__ __align__(1024) uint16_t Bs_[2 * 256 * 64];
  const int tid = threadIdx.x;
  const int wid = tid >> 6, l = tid & 63;
  const int wr = wid >> 2, wc = wid & 3;
  const int n0 = blockIdx.x * 256, m0 = blockIdx.y * 256;
  const size_t kbase = blockIdx.z * 1024;
  const int lrow = l >> 3, lcb = (l & 7) * 16;

  auto stA = [&](int t, int h) {
    int ta = (t < NT) ? t : (t - NT);
    const char* g = (const char*)A +
        ((size_t)(m0 + h * 128 + wid * 16 + lrow) * K + kbase + ta * 64) * 2 + lcb;
    char* s = (char*)As_ + (t & 1) * 32768 + h * 16384 + wid * 2048;
    gload_lds16(g, s);
    gload_lds16(g + (size_t)8 * K * 2, s + 1024);
  };
  auto stB = [&](int t, int h) {
    int ta = (t < NT) ? t : (t - NT);
    const char* g = (const char*)W +
        ((size_t)(n0 + h * 128 + wid * 16 + lrow) * K + kbase + ta * 64) * 2 + lcb;
    char* s = (char*)Bs_ + (t & 1) * 32768 + h * 16384 + wid * 2048;
    gload_lds16(g, s);
    gload_lds16(g + (size_t)8 * K * 2, s + 1024);
  };

  const int cb0 = (((l >> 4) << 4)) ^ ((l & 7) << 4);
  const int cb1 = (64 + ((l >> 4) << 4)) ^ ((l & 7) << 4);

  const f32x4 Z4 = {0.f, 0.f, 0.f, 0.f};
  f32x4 acc[8][4];
  #pragma unroll
  for (int i = 0; i < 8; ++i)
    #pragma unroll
    for (int j = 0; j < 4; ++j) acc[i][j] = Z4;
  s16x8 bfr[4][2];

#define VMW asm volatile("s_waitcnt vmcnt(6)" ::: "memory")
#define PHASE(DB, Q, READB, STG) {                                          \
    const char* abase = (const char*)As_ + (DB) * 32768;                    \
    s16x8 af[2][2];                                                         \
    _Pragma("unroll") for (int mm = 0; mm < 2; ++mm) {                      \
      int arow = ((2 * (2 * (Q) + mm) + wr) * 16 + (l & 15)) * 128;         \
      af[mm][0] = *(const s16x8*)(abase + arow + cb0);                      \
      af[mm][1] = *(const s16x8*)(abase + arow + cb1);                      \
    }                                                                       \
    if (READB) {                                                            \
      const char* bbase = (const char*)Bs_ + (DB) * 32768;                  \
      _Pragma("unroll") for (int nn = 0; nn < 4; ++nn) {                    \
        int brow = (wc * 64 + nn * 16 + (l & 15)) * 128;                    \
        bfr[nn][0] = *(const s16x8*)(bbase + brow + cb0);                   \
        bfr[nn][1] = *(const s16x8*)(bbase + brow + cb1);                   \
      }                                                                     \
    }                                                                       \
    STG;                                                                    \
    __builtin_amdgcn_s_barrier();                                           \
    asm volatile("s_waitcnt lgkmcnt(0)" ::: "memory");                      \
    __builtin_amdgcn_sched_barrier(0);                                      \
    __builtin_amdgcn_s_setprio(1);                                          \
    _Pragma("unroll") for (int mm = 0; mm < 2; ++mm)                        \
      _Pragma("unroll") for (int nn = 0; nn < 4; ++nn) {                    \
        acc[2 * (Q) + mm][nn] = mfma16(af[mm][0], bfr[nn][0], acc[2 * (Q) + mm][nn]); \
        acc[2 * (Q) + mm][nn] = mfma16(af[mm][1], bfr[nn][1], acc[2 * (Q) + mm][nn]); \
      }                                                                     \
    __builtin_amdgcn_s_setprio(0);                                          \
    __builtin_amdgcn_s_barrier();                                           \
  }

  stB(0, 0); stA(0, 0); stB(0, 1); stA(0, 1);
  stB(1, 0); stA(1, 0); stB(1, 1);
  VMW;
  __builtin_amdgcn_s_barrier();

  for (int it = 0; it < NT / 2; ++it) {
    int t0 = 2 * it, t1 = t0 + 1;
    PHASE(0, 0, 1, stA(t1, 1));
    PHASE(0, 1, 0, stB(t0 + 2, 0));
    PHASE(0, 2, 0, stA(t0 + 2, 0));
    PHASE(0, 3, 0, { stB(t0 + 2, 1); VMW; });
    PHASE(1, 0, 1, stA(t0 + 2, 1));
    PHASE(1, 1, 0, stB(t1 + 2, 0));
    PHASE(1, 2, 0, stA(t1 + 2, 0));
    PHASE(1, 3, 0, { stB(t1 + 2, 1); VMW; });
  }
  asm volatile("s_waitcnt vmcnt(0)" ::: "memory");
  __builtin_amdgcn_s_barrier();
#undef PHASE
#undef VMW

  float* po = pout + (size_t)blockIdx.z * 2048 * 2048;
  #pragma unroll
  for (int mf = 0; mf < 8; ++mf)
    #pragma unroll
    for (int nf = 0; nf < 4; ++nf)
      #pragma unroll
      for (int r = 0; r < 4; ++r) {
        int row = m0 + (2 * mf + wr) * 16 + ((l >> 4) << 2) + r;
        int col = n0 + wc * 64 + nf * 16 + (l & 15);
        po[(size_t)row * 2048 + col] = acc[mf][nf][r];
      }
}

// -------- reduce split-K partials + RoPE(k) -> kvbuf bf16 [2048][2048] -----
__global__ __launch_bounds__(256) void k_redrope(const float* __restrict__ p,
    uint16_t* __restrict__ kv)
{
  int t = blockIdx.x, tid = threadIdx.x;
  const size_t zs = (size_t)2048 * 2048;
  auto sum4 = [&](int c) -> float {
    size_t o = (size_t)t * 2048 + c;
    return p[o] + p[o + zs] + p[o + 2 * zs] + p[o + 3 * zs];
  };
  float pos = (float)(t & (SEQ - 1));
  for (int pi = tid; pi < 512; pi += 256) {
    int hh = pi >> 6, j = pi & 63;
    int c1 = hh * 128 + j, c2 = c1 + 64;
    float s1 = sum4(c1), s2 = sum4(c2);
    float f = pos * expf(-(float)j * 0.14391156831212787f);
    float sn, cs;
    sincosf(f, &sn, &cs);
    kv[(size_t)t * 2048 + c1] = f2bf(s1 * cs - s2 * sn);
    kv[(size_t)t * 2048 + c2] = f2bf(s2 * cs + s1 * sn);
  }
  for (int c = 1024 + tid; c < 2048; c += 256)
    kv[(size_t)t * 2048 + c] = f2bf(sum4(c));
}

// -------- gather r (rms1 out) at last tokens, unswizzle -> f32 [4][4096] ---
__global__ __launch_bounds__(256) void k_prep_r4(const uint16_t* __restrict__ rbuf,
    const int* __restrict__ lastb, float* __restrict__ r4f)
{
  int r = blockIdx.x;
  int t = r * SEQ + lastb[r];
  const uint16_t* src = rbuf + (size_t)t * DMODEL;
  for (int k = threadIdx.x * 8; k < DMODEL; k += 2048) {
    int so = (k & ~63) | (((((k >> 3) & 7) ^ (t & 7))) << 3);
    u16x8 v = *(const u16x8*)(src + so);
    #pragma unroll
    for (int j = 0; j < 8; ++j) r4f[r * DMODEL + k + j] = bf2f(v[j]);
  }
}

// -------- 4-row fused dequant GEMV: out[r][n] = (base?) + a4[r] . W[n] -----
template<int MODE>
__global__ __launch_bounds__(256) void k_gemv4(const int* __restrict__ idx,
    const float* __restrict__ am, const float* __restrict__ a4,
    float* __restrict__ out, const float* __restrict__ table,
    const int* __restrict__ ids, const int* __restrict__ lastb)
{
  __shared__ float As[4 * 4096];
  __shared__ float code[16];
  if (threadIdx.x < 16) code[threadIdx.x] = NF4_TAB[threadIdx.x];
  for (int i = threadIdx.x * 4; i < 4 * 4096; i += 1024)
    *(float4*)(As + i) = *(const float4*)(a4 + i);
  __syncthreads();
  int wv = threadIdx.x >> 6, l = threadIdx.x & 63;
  int lhi = l >> 4;
  for (int n = blockIdx.x * 4 + wv; n < 4096; n += gridDim.x * 4) {
    const int4* ip = (const int4*)(idx + (size_t)n * 4096);
    const float* ap = am + (size_t)n * 64;
    float a0 = 0.f, a1 = 0.f, a2 = 0.f, a3 = 0.f;
    #pragma unroll
    for (int kk = 0; kk < 16; ++kk) {
      int4 iv = ip[kk * 64 + l];
      float sc = ap[kk * 4 + lhi];
      float w0 = code[iv.x] * sc, w1 = code[iv.y] * sc;
      float w2 = code[iv.z] * sc, w3 = code[iv.w] * sc;
      const float* A0 = As + kk * 256 + l * 4;
      f32x4 v0 = *(const f32x4*)A0;
      f32x4 v1 = *(const f32x4*)(A0 + 4096);
      f32x4 v2 = *(const f32x4*)(A0 + 8192);
      f32x4 v3 = *(const f32x4*)(A0 + 12288);
      a0 = fmaf(w0, v0[0], fmaf(w1, v0[1], fmaf(w2, v0[2], fmaf(w3, v0[3], a0))));
      a1 = fmaf(w0, v1[0], fmaf(w1, v1[1], fmaf(w2, v1[2], fmaf(w3, v1[3], a1))));
      a2 = fmaf(w0, v2[0], fmaf(w1, v2[1], fmaf(w2, v2[2], fmaf(w3, v2[3], a2))));
      a3 = fmaf(w0, v3[0], fmaf(w1, v3[1], fmaf(w2, v3[2], fmaf(w3, v3[3], a3))));
    }
    #pragma unroll
    for (int off = 1; off < 64; off <<= 1) {
      a0 += __shfl_xor(a0, off); a1 += __shfl_xor(a1, off);
      a2 += __shfl_xor(a2, off); a3 += __shfl_xor(a3, off);
    }
    if (l == 0) {
      float av[4] = {a0, a1, a2, a3};
      #pragma unroll
      for (int r = 0; r < 4; ++r) {
        float base = 0.f;
        if (MODE == 1)
          base = table[(size_t)ids[r * SEQ + lastb[r]] * DMODEL + n];
        out[r * 4096 + n] = base + av[r];
      }
    }
  }
}

// -------- fused gate+up 4-row GEMV: hm[r][n] = silu(g)*u -------------------
__global__ __launch_bounds__(256) void k_gemv_gu(const int* __restrict__ idxg,
    const float* __restrict__ amg, const int* __restrict__ idxu,
    const float* __restrict__ amu, const float* __restrict__ a4,
    uint16_t* __restrict__ hm)
{
  __shared__ float As[4 * 4096];
  __shared__ float code[16];
  if (threadIdx.x < 16) code[threadIdx.x] = NF4_TAB[threadIdx.x];
  for (int i = threadIdx.x * 4; i < 4 * 4096; i += 1024)
    *(float4*)(As + i) = *(const float4*)(a4 + i);
  __syncthreads();
  int wv = threadIdx.x >> 6, l = threadIdx.x & 63;
  int lhi = l >> 4;
  for (int n = blockIdx.x * 4 + wv; n < DFF; n += gridDim.x * 4) {
    const int4* ipg = (const int4*)(idxg + (size_t)n * 4096);
    const int4* ipu = (const int4*)(idxu + (size_t)n * 4096);
    const float* apg = amg + (size_t)n * 64;
    const float* apu = amu + (size_t)n * 64;
    float g0 = 0.f, g1 = 0.f, g2 = 0.f, g3 = 0.f;
    float u0 = 0.f, u1 = 0.f, u2 = 0.f, u3 = 0.f;
    #pragma unroll 8
    for (int kk = 0; kk < 16; ++kk) {
      int4 ig = ipg[kk * 64 + l];
      int4 iu = ipu[kk * 64 + l];
      float sg = apg[kk * 4 + lhi];
      float su = apu[kk * 4 + lhi];
      float wg0 = code[ig.x] * sg, wg1 = code[ig.y] * sg;
      float wg2 = code[ig.z] * sg, wg3 = code[ig.w] * sg;
      float wu0 = code[iu.x] * su, wu1 = code[iu.y] * su;
      float wu2 = code[iu.z] * su, wu3 = code[iu.w] * su;
      const float* A0 = As + kk * 256 + l * 4;
      f32x4 v0 = *(const f32x4*)A0;
      f32x4 v1 = *(const f32x4*)(A0 + 4096);
      f32x4 v2 = *(const f32x4*)(A0 + 8192);
      f32x4 v3 = *(const f32x4*)(A0 + 12288);
      g0 = fmaf(wg0, v0[0], fmaf(wg1, v0[1], fmaf(wg2, v0[2], fmaf(wg3, v0[3], g0))));
      g1 = fmaf(wg0, v1[0], fmaf(wg1, v1[1], fmaf(wg2, v1[2], fmaf(wg3, v1[3], g1))));
      g2 = fmaf(wg0, v2[0], fmaf(wg1, v2[1], fmaf(wg2, v2[2], fmaf(wg3, v2[3], g2))));
      g3 = fmaf(wg0, v3[0], fmaf(wg1, v3[1], fmaf(wg2, v3[2], fmaf(wg3, v3[3], g3))));
      u0 = fmaf(wu0, v0[0], fmaf(wu1, v0[1], fmaf(wu2, v0[2], fmaf(wu3, v0[3], u0))));
      u1 = fmaf(wu0, v1[0], fmaf(wu1, v1[1], fmaf(wu2, v1[2], fmaf(wu3, v1[3], u1))));
      u2 = fmaf(wu0, v2[0], fmaf(wu1, v2[1], fmaf(wu2, v2[2], fmaf(wu3, v2[3], u2))));
      u3 = fmaf(wu0, v3[0], fmaf(wu1, v3[1], fmaf(wu2, v3[2], fmaf(wu3, v3[3], u3))));
    }
    #pragma unroll
    for (int off = 1; off < 64; off <<= 1) {
      g0 += __shfl_xor(g0, off); g1 += __shfl_xor(g1, off);
      g2 += __shfl_xor(g2, off); g3 += __shfl_xor(g3, off);
      u0 += __shfl_xor(u0, off); u1 += __shfl_xor(u1, off);
      u2 += __shfl_xor(u2, off); u3 += __shfl_xor(u3, off);
    }
    if (l == 0) {
      float gv[4] = {g0, g1, g2, g3};
      float uv[4] = {u0, u1, u2, u3};
      #pragma unroll
      for (int r = 0; r < 4; ++r) {
        float g = gv[r];
        hm[(size_t)r * DFF + n] = f2bf((g / (1.f + __expf(-g))) * uv[r]);
      }
    }
  }
}

// -------- down 4-row GEMV (K=14336, a4 bf16 in LDS): h4f = h4 + dot --------
__global__ __launch_bounds__(256) void k_gemv_down(const int* __restrict__ idx,
    const float* __restrict__ am, const uint16_t* __restrict__ hm,
    const float* __restrict__ h4, float* __restrict__ h4f)
{
  __shared__ uint16_t As[4 * 14336];
  __shared__ float code[16];
  if (threadIdx.x < 16) code[threadIdx.x] = NF4_TAB[threadIdx.x];
  for (int i = threadIdx.x * 8; i < 4 * 14336; i += 2048)
    *(u16x8*)(As + i) = *(const u16x8*)(hm + i);
  __syncthreads();
  int wv = threadIdx.x >> 6, l = threadIdx.x & 63;
  int lhi = l >> 4;
  for (int n = blockIdx.x * 4 + wv; n < 4096; n += gridDim.x * 4) {
    const int4* ip = (const int4*)(idx + (size_t)n * 14336);
    const float* ap = am + (size_t)n * 224;
    float a0 = 0.f, a1 = 0.f, a2 = 0.f, a3 = 0.f;
    #pragma unroll 8
    for (int kk = 0; kk < 56; ++kk) {
      int4 iv = ip[kk * 64 + l];
      float sc = ap[kk * 4 + lhi];
      float w0 = code[iv.x] * sc, w1 = code[iv.y] * sc;
      float w2 = code[iv.z] * sc, w3 = code[iv.w] * sc;
      int k0 = kk * 256 + l * 4;
      const uint16_t* B0 = As + k0;
      #pragma unroll
      for (int r = 0; r < 4; ++r) {
        u16x8 hv8;
        *(uint2*)&hv8 = *(const uint2*)(B0 + r * 14336);
        float x0 = bf2f(hv8[0]), x1 = bf2f(hv8[1]);
        float x2 = bf2f(hv8[2]), x3 = bf2f(hv8[3]);
        float t = fmaf(w0, x0, fmaf(w1, x1, fmaf(w2, x2, w3 * x3)));
        if (r == 0) a0 += t; else if (r == 1) a1 += t;
        else if (r == 2) a2 += t; else a3 += t;
      }
    }
    #pragma unroll
    for (int off = 1; off < 64; off <<= 1) {
      a0 += __shfl_xor(a0, off); a1 += __shfl_xor(a1, off);
      a2 += __shfl_xor(a2, off); a3 += __shfl_xor(a3, off);
    }
    if (l == 0) {
      float av[4] = {a0, a1, a2, a3};
      #pragma unroll
      for (int r = 0; r < 4; ++r)
        h4f[r * 4096 + n] = h4[r * 4096 + n] + av[r];
    }
  }
}

// -------- 4-query attention (rope on q inside), f32 ------------------------
__global__ __launch_bounds__(256) void k_attn4(const float* __restrict__ q4,
    const uint16_t* __restrict__ kv, const int* __restrict__ maskp,
    const int* __restrict__ lastb, float* __restrict__ ao4)
{
  int hh = blockIdx.x, b = blockIdx.y;
  int kvh = hh >> 2;
  int tid = threadIdx.x;
  __shared__ float qs[128];
  __shared__ float sarr[512];
  __shared__ float red[256];
  __shared__ float oacc[2][128];
  int last = lastb[b];
  if (tid < 128) {
    int d = tid, j = d & 63;
    float f = (float)last * expf(-(float)j * 0.14391156831212787f);
    float sn, cs;
    sincosf(f, &sn, &cs);
    const float* q = q4 + b * 4096 + hh * 128;
    float v = (d < 64) ? (q[d] * cs - q[d + 64] * sn)
                       : (q[d] * cs + q[d - 64] * sn);
    qs[d] = v * 0.08838834764831845f;
  }
  __syncthreads();
  float sl[2];
  #pragma unroll
  for (int h2 = 0; h2 < 2; ++h2) {
    int jj = tid + h2 * 256;
    bool valid = (jj <= last) && (maskp[b * SEQ + jj] > 0);
    float s = -1e9f;
    if (valid) {
      s = 0.f;
      const uint16_t* kp = kv + ((size_t)(b * SEQ + jj)) * 2048 + kvh * 128;
      #pragma unroll
      for (int c = 0; c < 16; ++c) {
        u16x8 kvv = *(const u16x8*)(kp + c * 8);
        #pragma unroll
        for (int e = 0; e < 8; ++e)
          s = fmaf(qs[c * 8 + e], bf2f(kvv[e]), s);
      }
    }
    sarr[jj] = s;
    sl[h2] = s;
  }
  red[tid] = fmaxf(sl[0], sl[1]);
  __syncthreads();
  for (int s = 128; s > 0; s >>= 1) {
    if (tid < s) red[tid] = fmaxf(red[tid], red[tid + s]);
    __syncthreads();
  }
  float m = red[0];
  __syncthreads();
  float ps = 0.f;
  #pragma unroll
  for (int h2 = 0; h2 < 2; ++h2) {
    int jj = tid + h2 * 256;
    float pe = __expf(sarr[jj] - m);
    ps += pe;
    sarr[jj] = pe;
  }
  red[tid] = ps;
  __syncthreads();
  for (int s = 128; s > 0; s >>= 1) {
    if (tid < s) red[tid] += red[tid + s];
    __syncthreads();
  }
  float inv = 1.f / red[0];
  __syncthreads();
  int half = tid >> 7, d = tid & 127;
  float acc = 0.f;
  const uint16_t* vp = kv + ((size_t)(b * SEQ + half * 256)) * 2048 + 1024 + kvh * 128 + d;
  for (int j = 0; j < 256; ++j)
    acc = fmaf(sarr[half * 256 + j], bf2f(vp[(size_t)j * 2048]), acc);
  oacc[half][d] = acc;
  __syncthreads();
  if (tid < 128)
    ao4[b * 4096 + hh * 128 + tid] = (oacc[0][tid] + oacc[1][tid]) * inv;
}

// -------- rms2 on 4 rows ----------------------------------------------------
__global__ __launch_bounds__(256) void k_rms2(const float* __restrict__ h4,
    const float* __restrict__ w, float* __restrict__ r2f)
{
  int b = blockIdx.x, tid = threadIdx.x;
  int wv = tid >> 6, l = tid & 63;
  int d0 = tid * 16;
  const float* src = h4 + b * 4096;
  float vals[16];
  float ss = 0.f;
  #pragma unroll
  for (int i = 0; i < 4; ++i) {
    float4 v4 = *(const float4*)(src + d0 + i * 4);
    vals[i*4+0] = v4.x; vals[i*4+1] = v4.y; vals[i*4+2] = v4.z; vals[i*4+3] = v4.w;
    ss += v4.x*v4.x + v4.y*v4.y + v4.z*v4.z + v4.w*v4.w;
  }
  #pragma unroll
  for (int off = 1; off < 64; off <<= 1) ss += __shfl_xor(ss, off);
  __shared__ float red[4];
  if (l == 0) red[wv] = ss;
  __syncthreads();
  float rs = rsqrtf((red[0]+red[1]+red[2]+red[3]) * (1.f/4096.f) + 1e-5f);
  #pragma unroll
  for (int i = 0; i < 16; ++i)
    r2f[b * 4096 + d0 + i] = vals[i] * rs * w[d0 + i];
}

// -------- pool (parallel): one block per output column o -------------------
// wave wv computes dot(h4f[wv], dpw[o]) and ||h4f[wv]||; lane0 combines.
__global__ __launch_bounds__(256) void k_pool3(const float* __restrict__ h4f,
    const float* __restrict__ dpw, const float* __restrict__ dpb,
    float* __restrict__ out)
{
  int o = blockIdx.x;
  int tid = threadIdx.x, wv = tid >> 6, l = tid & 63;
  __shared__ float dsh[4], nsh[4];
  const float* row = h4f + wv * 4096;
  const float* wrow = dpw + (size_t)o * 4096;
  float d1 = 0.f, ss = 0.f;
  for (int d = l * 4; d < 4096; d += 256) {
    float4 v = *(const float4*)(row + d);
    float4 u = *(const float4*)(wrow + d);
    d1 += v.x*u.x + v.y*u.y + v.z*u.z + v.w*u.w;
    ss += v.x*v.x + v.y*v.y + v.z*v.z + v.w*v.w;
  }
  #pragma unroll
  for (int off = 1; off < 64; off <<= 1) {
    d1 += __shfl_xor(d1, off);
    ss += __shfl_xor(ss, off);
  }
  if (l == 0) { dsh[wv] = d1; nsh[wv] = fmaxf(sqrtf(ss), 1e-12f); }
  __syncthreads();
  if (tid < 2) {
    float b = dpb[o];
    float e1 = dsh[tid] / nsh[tid] + b;
    float e2 = dsh[tid + 2] / nsh[tid + 2] + b;
    out[tid * 50 + o] = e1 * e2;
  }
}

// ---------------------------------------------------------------------------
extern "C" void kernel_launch(void* const* d_in, const int* in_sizes, int n_in,
                              void* d_out, int out_size, void* d_ws, size_t ws_size,
                              hipStream_t stream) {
  const int*   ids   = (const int*)d_in[0];
  const int*   maskp = (const int*)d_in[1];
  const float* table = (const float*)d_in[2];
  const int* idxp[7];
  const float* amp[7];
  if (in_sizes[4] == in_sizes[3] / 64) {
    for (int i = 0; i < 7; ++i) {
      idxp[i] = (const int*)d_in[3 + 2 * i];
      amp[i]  = (const float*)d_in[4 + 2 * i];
    }
  } else {
    for (int i = 0; i < 7; ++i) {
      idxp[i] = (const int*)d_in[3 + i];
      amp[i]  = (const float*)d_in[10 + i];
    }
  }
  const float* rms1 = (const float*)d_in[17];
  const float* rms2w = (const float*)d_in[18];
  const float* dpw  = (const float*)d_in[19];
  const float* dpb  = (const float*)d_in[20];
  float* out = (float*)d_out;

  char* p = (char*)d_ws;
  int*      lastb = (int*)p;      p += 256;
  float*    r4f   = (float*)p;    p += 4 * 4096 * 4;
  float*    q4    = (float*)p;    p += 4 * 4096 * 4;
  float*    ao4   = (float*)p;    p += 4 * 4096 * 4;
  float*    h4    = (float*)p;    p += 4 * 4096 * 4;
  float*    r2f   = (float*)p;    p += 4 * 4096 * 4;
  float*    h4f   = (float*)p;    p += 4 * 4096 * 4;
  uint16_t* hm4   = (uint16_t*)p; p += 4 * DFF * 2 + 512;
  uint16_t* kvbuf = (uint16_t*)p; p += (size_t)TOK * 2048 * 2;       // 8 MiB
  uint16_t* rbuf  = (uint16_t*)p; p += (size_t)TOK * DMODEL * 2;     // 16 MiB
  uint16_t* wbuf  = (uint16_t*)p; p += (size_t)2048 * DMODEL * 2;    // 16 MiB
  float*    pbuf  = (float*)p;    p += (size_t)4 * 2048 * 2048 * 4;  // 64 MiB

  k_last<<<1, 256, 0, stream>>>(maskp, lastb);
  k_rms<<<TOK, 256, 0, stream>>>(ids, table, rms1, rbuf);

  // K,V projections (all tokens) via MFMA split-K GEMM
  k_dequant<<<2048, 256, 0, stream>>>(idxp[1], amp[1], wbuf, 1024 * DMODEL, DMODEL);
  k_dequant<<<2048, 256, 0, stream>>>(idxp[2], amp[2], wbuf + (size_t)1024 * DMODEL, 1024 * DMODEL, DMODEL);
  k_gemmkv<<<dim3(8, 8, 4), 512, 0, stream>>>(rbuf, wbuf, pbuf);
  k_redrope<<<TOK, 256, 0, stream>>>(pbuf, kvbuf);

  // Q at the 4 last tokens
  k_prep_r4<<<4, 256, 0, stream>>>(rbuf, lastb, r4f);
  k_gemv4<0><<<512, 256, 0, stream>>>(idxp[0], amp[0], r4f, q4, nullptr, nullptr, nullptr);

  // attention for 4 queries
  k_attn4<<<dim3(32, 4), 256, 0, stream>>>(q4, kvbuf, maskp, lastb, ao4);

  // O projection + embed residual -> h4
  k_gemv4<1><<<512, 256, 0, stream>>>(idxp[3], amp[3], ao4, h4, table, ids, lastb);

  // rms2 + MLP on 4 rows
  k_rms2<<<4, 256, 0, stream>>>(h4, rms2w, r2f);
  k_gemv_gu<<<448, 256, 0, stream>>>(idxp[4], amp[4], idxp[5], amp[5], r2f, hm4);
  k_gemv_down<<<256, 256, 0, stream>>>(idxp[6], amp[6], hm4, h4, h4f);

  // pool + normalize + project + pairwise product
  k_pool3<<<50, 256, 0, stream>>>(h4f, dpw, dpb, out);
}